// Round 1
// baseline (12163.026 us; speedup 1.0000x reference)
//
#include <hip/hip_runtime.h>
#include <hip/hip_cooperative_groups.h>

namespace cg = cooperative_groups;

// Problem: new_LSTM_30365418783418  (B=128, T=256, I=512, H=1024)
// R5: persistent cooperative kernel for the 256-step recurrence.
//  - 256 blocks x 256 threads (4 waves), 1 block/CU, grid.sync() per step.
//  - Block nb owns h-cols nb*4..nb*4+3 for all 5 gates (20 Whb rows).
//    Gates i,f,g,o (16 rows) live in 128 VGPRs/wave; gate d (4 rows, padded
//    to 16) lives in 32KB LDS as pre-packed MFMA fragments. Loaded ONCE.
//  - c-state slice in LDS across the whole chunk; elementwise block-local.
//  - Old per-step lstm_step kept as fallback if cooperative launch fails.
//
// d_in: 0:x 1:x_d 2:hidden 3:cell | 4..9: Wii,Wif,Wig,Wio,Wid,Wro (H,I)
//       10..14: Whi,Whf,Whg,Who,Whd (H,H) | 15..20: bi,bf,bg,bo,bd,Wrb (H,)
// d_out: y(128,256,1024) ++ h_last(128,1024) ++ c_last(128,1024), float32.

using bf16x8 = __attribute__((ext_vector_type(8))) __bf16;
using f32x4  = __attribute__((ext_vector_type(4))) float;

#define MFMA16(a, b, c) __builtin_amdgcn_mfma_f32_16x16x32_bf16(a, b, c, 0, 0, 0)

static __device__ __forceinline__ float b2f(ushort u) {
  union { unsigned int i; float f; } v; v.i = ((unsigned int)u) << 16; return v.f;
}
static __device__ __forceinline__ ushort f2b(float f) {
  union { float f; unsigned int i; } v; v.f = f;
  unsigned int x = v.i;
  return (ushort)((x + 0x7fffu + ((x >> 16) & 1u)) >> 16);  // RNE
}
static __device__ __forceinline__ float sigm(float x) {
  return 1.0f / (1.0f + __expf(-x));
}
static __device__ __forceinline__ float tanhfast(float x) {
  float e = __expf(2.0f * x);          // tanh = 1 - 2/(e^{2x}+1); saturates
  return 1.0f - 2.0f / (e + 1.0f);
}

// ---------------------------------------------------------------------------
// f32 -> bf16 conversion, 4 elems/thread. n % 4 == 0.
// ---------------------------------------------------------------------------
__global__ __launch_bounds__(256) void cvt_kernel(const float* __restrict__ src,
                                                  ushort* __restrict__ dst, int n)
{
  int i = (blockIdx.x * 256 + threadIdx.x) * 4;
  if (i < n) {
    float4 v = *(const float4*)(src + i);
    ushort4 o;
    o.x = f2b(v.x); o.y = f2b(v.y); o.z = f2b(v.z); o.w = f2b(v.w);
    *(ushort4*)(dst + i) = o;
  }
}

// ---------------------------------------------------------------------------
// Generic 128x128 NT bf16 GEMM K-loop, plain-load LDS staging.
// ---------------------------------------------------------------------------
static __device__ __forceinline__ void gemm_kloop(
    const ushort* __restrict__ A, int lda,
    const ushort* __restrict__ Bw, int ldb, int K,
    ushort* As, ushort* Bs, f32x4 (&acc)[4][4])
{
  const int tid = threadIdx.x;
  const int l = tid & 63, w = tid >> 6;
  const int wm = (w >> 1) * 64, wn = (w & 1) * 64;
  const int lr = l & 15, quad = l >> 4;
  bf16x8* Asv = (bf16x8*)As;
  bf16x8* Bsv = (bf16x8*)Bs;
  for (int k0 = 0; k0 < K; k0 += 32) {
    __syncthreads();
#pragma unroll
    for (int it = 0; it < 2; ++it) {
      int c = it * 256 + tid;
      int row = c >> 2, seg = c & 3;
      Asv[c] = *(const bf16x8*)(A  + row * lda + k0 + seg * 8);
      Bsv[c] = *(const bf16x8*)(Bw + row * ldb + k0 + seg * 8);
    }
    __syncthreads();
    bf16x8 af[4], bfr[4];
#pragma unroll
    for (int i = 0; i < 4; ++i) af[i]  = Asv[(wm + i * 16 + lr) * 4 + quad];
#pragma unroll
    for (int j = 0; j < 4; ++j) bfr[j] = Bsv[(wn + j * 16 + lr) * 4 + quad];
#pragma unroll
    for (int i = 0; i < 4; ++i)
#pragma unroll
      for (int j = 0; j < 4; ++j)
        acc[i][j] = MFMA16(af[i], bfr[j], acc[i][j]);
  }
}

// ---------------------------------------------------------------------------
// Kernel 1 (per chunk): P[m'][g*1024+h] = bf16( A[b, t0+tt] . Wg[h] + bias )
// m' = b*chunk + tt. Grid (chunk, 40), 256 threads.
// ---------------------------------------------------------------------------
__global__ __launch_bounds__(256) void gemm_pre(
    const ushort* __restrict__ xb, const ushort* __restrict__ xdb,
    const ushort* __restrict__ Wb,      // 6x(1024x512) contiguous (Wii..Wid,Wro)
    const float* __restrict__ bias5, ushort* __restrict__ P,
    int t0, int lc)
{
  __shared__ __align__(16) ushort As[4096], Bs[4096];
  const int m0 = blockIdx.x * 128;
  const int n0 = blockIdx.y * 128;
  const int g = n0 >> 10;
  const ushort* A = (g == 4) ? xdb : xb;
  const ushort* Bw = Wb + g * 524288 + (n0 & 1023) * 512;
  const int cm1 = (1 << lc) - 1;

  const int tid = threadIdx.x;
  const int l = tid & 63, w = tid >> 6;
  const int wm = (w >> 1) * 64, wn = (w & 1) * 64;
  const int lr = l & 15, quad = l >> 4;
  f32x4 acc[4][4] = {};
  bf16x8* Asv = (bf16x8*)As;
  bf16x8* Bsv = (bf16x8*)Bs;

  for (int k0 = 0; k0 < 512; k0 += 32) {
    __syncthreads();
#pragma unroll
    for (int it = 0; it < 2; ++it) {
      int c = it * 256 + tid;
      int row = c >> 2, seg = c & 3;
      int gr = m0 + row;                              // m' row
      int arow = ((gr >> lc) << 8) + t0 + (gr & cm1); // b*T + t
      Asv[c] = *(const bf16x8*)(A  + arow * 512 + k0 + seg * 8);
      Bsv[c] = *(const bf16x8*)(Bw + row  * 512 + k0 + seg * 8);
    }
    __syncthreads();
    bf16x8 af[4], bfr[4];
#pragma unroll
    for (int i = 0; i < 4; ++i) af[i]  = Asv[(wm + i * 16 + lr) * 4 + quad];
#pragma unroll
    for (int j = 0; j < 4; ++j) bfr[j] = Bsv[(wn + j * 16 + lr) * 4 + quad];
#pragma unroll
    for (int i = 0; i < 4; ++i)
#pragma unroll
      for (int j = 0; j < 4; ++j)
        acc[i][j] = MFMA16(af[i], bfr[j], acc[i][j]);
  }

#pragma unroll
  for (int i = 0; i < 4; ++i)
#pragma unroll
    for (int j = 0; j < 4; ++j) {
      int row = m0 + wm + i * 16 + quad * 4;   // C/D: row = quad*4+reg (m89)
      int col = n0 + wn + j * 16 + lr;         //      col = lane&15
      float bias = bias5[col];
#pragma unroll
      for (int r = 0; r < 4; ++r)
        P[(row + r) * 5120 + col] = f2b(acc[i][j][r] + bias);
    }
}

// ---------------------------------------------------------------------------
// R5 persistent recurrent kernel (cooperative). Grid 256 x 256 threads.
// Block nb owns h-cols nb*4..+3, all 5 gates (20 Whb rows):
//   local rows 0..15  = gates 0..3 x hc 0..3  -> B0 in VGPRs (128/wave)
//   local rows 16..19 = gate 4    x hc 0..3  -> Bs1 in LDS (rows 20..31 = 0)
// Per step: C[128 x 20] = h @ Wslice^T, wave w owns batch rows w*32..w*32+31.
// ---------------------------------------------------------------------------
__global__ __launch_bounds__(256, 1) void lstm_chunk(
    ushort* __restrict__ hA, ushort* __restrict__ hB,
    float* __restrict__ cbuf, const ushort* __restrict__ Whb,
    const ushort* __restrict__ P, ushort* __restrict__ hs,
    int t0, int nt, int lc)
{
  __shared__ __align__(16) ushort Bs1[32 * 64 * 8];   // 32 ksteps x 64 lanes x 8 bf16 = 32KB
  __shared__ float Pls[128 * 21];                     // preacts, pad stride 21 = 10.5KB
  __shared__ float cs[128 * 5];                       // cell slice, pad stride 5 = 2.5KB

  const int tid = threadIdx.x;
  const int l = tid & 63, w = tid >> 6;
  const int lr = l & 15, quad = l >> 4;
  const int nb = blockIdx.x;                          // 0..255

  // ---- B0: rows 0..15 (g = lr>>2, hc = lr&3) into registers, once ----
  bf16x8 B0[32];
  {
    const ushort* wp = Whb + ((lr >> 2) * 1024 + nb * 4 + (lr & 3)) * 1024 + quad * 8;
#pragma unroll
    for (int k = 0; k < 32; ++k)
      B0[k] = *(const bf16x8*)(wp + k * 32);
  }
  // ---- Bs1: rows 16..19 = gate 4 (valid lanes lr<4), rows 20..31 zero ----
  {
    const ushort* wp = Whb + (4096 + nb * 4 + (lr & 3)) * 1024 + quad * 8;
#pragma unroll
    for (int kk = 0; kk < 8; ++kk) {
      int k = w * 8 + kk;
      bf16x8 v = {};
      if (lr < 4) v = *(const bf16x8*)(wp + k * 32);
      *(bf16x8*)(Bs1 + (k * 64 + l) * 8) = v;
    }
  }
  // ---- cell slice -> LDS ----
  if (tid < 128) {
    float4 cv = *(const float4*)(cbuf + tid * 1024 + nb * 4);
    cs[tid * 5 + 0] = cv.x; cs[tid * 5 + 1] = cv.y;
    cs[tid * 5 + 2] = cv.z; cs[tid * 5 + 3] = cv.w;
  }
  __syncthreads();

  cg::grid_group grid = cg::this_grid();
  const int aoff = (w * 32 + lr) * 1024 + quad * 8;
  const bf16x8* Bs1v = (const bf16x8*)Bs1;

  for (int tt = 0; tt < nt; ++tt) {
    const ushort* hr = (tt & 1) ? hB : hA;
    ushort* hw       = (tt & 1) ? hA : hB;

    f32x4 acc[2][2] = {};
#pragma unroll
    for (int k = 0; k < 32; ++k) {
      bf16x8 a0 = *(const bf16x8*)(hr + aoff + k * 32);
      bf16x8 a1 = *(const bf16x8*)(hr + aoff + 16384 + k * 32);
      bf16x8 b1 = Bs1v[k * 64 + l];
      acc[0][0] = MFMA16(a0, B0[k], acc[0][0]);
      acc[1][0] = MFMA16(a1, B0[k], acc[1][0]);
      acc[0][1] = MFMA16(a0, b1, acc[0][1]);
      acc[1][1] = MFMA16(a1, b1, acc[1][1]);
    }

    // C/D mapping (m89): row = quad*4+reg, col = lane&15
#pragma unroll
    for (int i = 0; i < 2; ++i) {
      int b = w * 32 + i * 16 + quad * 4;
#pragma unroll
      for (int r = 0; r < 4; ++r)
        Pls[(b + r) * 21 + lr] = acc[i][0][r];
      if (lr < 4) {
#pragma unroll
        for (int r = 0; r < 4; ++r)
          Pls[(b + r) * 21 + 16 + lr] = acc[i][1][r];
      }
    }
    __syncthreads();

    if (tid < 128) {
      const int b = tid;
      const int prow = ((b << lc) + tt) * 5120 + nb * 4;
      ushort4 p0 = *(const ushort4*)(P + prow);
      ushort4 p1 = *(const ushort4*)(P + prow + 1024);
      ushort4 p2 = *(const ushort4*)(P + prow + 2048);
      ushort4 p3 = *(const ushort4*)(P + prow + 3072);
      ushort4 p4 = *(const ushort4*)(P + prow + 4096);
      const float* pr = Pls + b * 21;
      ushort hv0, hv1, hv2, hv3;
#pragma unroll
      for (int hc = 0; hc < 4; ++hc) {
        float pi = b2f(((const ushort*)&p0)[hc]) + pr[0 + hc];
        float pf = b2f(((const ushort*)&p1)[hc]) + pr[4 + hc];
        float pg = b2f(((const ushort*)&p2)[hc]) + pr[8 + hc];
        float po = b2f(((const ushort*)&p3)[hc]) + pr[12 + hc];
        float pd = b2f(((const ushort*)&p4)[hc]) + pr[16 + hc];
        float ig = sigm(pi), fg = sigm(pf), gg = tanhfast(pg);
        float og = sigm(po), dg = sigm(pd);
        float cnew = fg * cs[b * 5 + hc] + ig * gg + dg;
        cs[b * 5 + hc] = cnew;
        ushort hb16 = f2b(og * tanhfast(cnew));
        if (hc == 0) hv0 = hb16; else if (hc == 1) hv1 = hb16;
        else if (hc == 2) hv2 = hb16; else hv3 = hb16;
      }
      ushort4 hvv; hvv.x = hv0; hvv.y = hv1; hvv.z = hv2; hvv.w = hv3;
      *(ushort4*)(hw + b * 1024 + nb * 4) = hvv;
      *(ushort4*)(hs + (b * 256 + t0 + tt) * 1024 + nb * 4) = hvv;
    }
    grid.sync();
  }

  // ---- cell slice back to global ----
  if (tid < 128) {
    float4 cv;
    cv.x = cs[tid * 5 + 0]; cv.y = cs[tid * 5 + 1];
    cv.z = cs[tid * 5 + 2]; cv.w = cs[tid * 5 + 3];
    *(float4*)(cbuf + tid * 1024 + nb * 4) = cv;
  }
}

// ---------------------------------------------------------------------------
// Fallback kernel (x256): one LSTM step. Grid (4,64) x 64 threads.
// ---------------------------------------------------------------------------
__global__ __launch_bounds__(64) void lstm_step(
    const ushort* __restrict__ hprev, ushort* __restrict__ hnext,
    float* __restrict__ cbuf, const ushort* __restrict__ Whb,
    const ushort* __restrict__ P, ushort* __restrict__ hs,
    int t, int tloc, int lc)
{
  const int l = threadIdx.x;
  const int m0 = blockIdx.x * 32;
  const int hc = blockIdx.y * 16;
  const int lr = l & 15, quad = l >> 4;

  f32x4 acc[2][5] = {};
  const ushort* a0p = hprev + (m0 + lr) * 1024 + quad * 8;
  const ushort* a1p = a0p + 16 * 1024;
  const ushort* wp = Whb + (hc + lr) * 1024 + quad * 8;

#pragma unroll 2
  for (int k0 = 0; k0 < 1024; k0 += 32) {
    bf16x8 a0 = *(const bf16x8*)(a0p + k0);
    bf16x8 a1 = *(const bf16x8*)(a1p + k0);
    bf16x8 b0 = *(const bf16x8*)(wp + k0);
    bf16x8 b1 = *(const bf16x8*)(wp + 1048576 + k0);
    bf16x8 b2 = *(const bf16x8*)(wp + 2097152 + k0);
    bf16x8 b3 = *(const bf16x8*)(wp + 3145728 + k0);
    bf16x8 b4 = *(const bf16x8*)(wp + 4194304 + k0);
    acc[0][0] = MFMA16(a0, b0, acc[0][0]);
    acc[1][0] = MFMA16(a1, b0, acc[1][0]);
    acc[0][1] = MFMA16(a0, b1, acc[0][1]);
    acc[1][1] = MFMA16(a1, b1, acc[1][1]);
    acc[0][2] = MFMA16(a0, b2, acc[0][2]);
    acc[1][2] = MFMA16(a1, b2, acc[1][2]);
    acc[0][3] = MFMA16(a0, b3, acc[0][3]);
    acc[1][3] = MFMA16(a1, b3, acc[1][3]);
    acc[0][4] = MFMA16(a0, b4, acc[0][4]);
    acc[1][4] = MFMA16(a1, b4, acc[1][4]);
  }

  const int h = hc + lr;
#pragma unroll
  for (int i = 0; i < 2; ++i) {
#pragma unroll
    for (int r = 0; r < 4; ++r) {
      int b = m0 + i * 16 + quad * 4 + r;
      int prow = ((b << lc) + tloc) * 5120;
      float pi = b2f(P[prow + h])          + acc[i][0][r];
      float pf = b2f(P[prow + 1024 + h])   + acc[i][1][r];
      float pg = b2f(P[prow + 2048 + h])   + acc[i][2][r];
      float po = b2f(P[prow + 3072 + h])   + acc[i][3][r];
      float pd = b2f(P[prow + 4096 + h])   + acc[i][4][r];
      float ig = sigm(pi), fg = sigm(pf), gg = tanhfast(pg);
      float og = sigm(po), dg = sigm(pd);
      float cold = cbuf[b * 1024 + h];
      float cnew = fg * cold + ig * gg + dg;
      cbuf[b * 1024 + h] = cnew;
      ushort hb = f2b(og * tanhfast(cnew));
      hnext[b * 1024 + h] = hb;
      hs[(b * 256 + t) * 1024 + h] = hb;
    }
  }
}

// ---------------------------------------------------------------------------
// Kernel 3: y = tanh(x@Wro^T + hs@Who^T + Wrb), f32 out. Grid (256, 8).
// ---------------------------------------------------------------------------
__global__ __launch_bounds__(256) void gemm_post(
    const ushort* __restrict__ xb, const ushort* __restrict__ hs,
    const ushort* __restrict__ Wrob, const ushort* __restrict__ Whob,
    const float* __restrict__ Wrb, float* __restrict__ y)
{
  __shared__ __align__(16) ushort As[4096], Bs[4096];
  const int m0 = blockIdx.x * 128;
  const int n0 = blockIdx.y * 128;
  f32x4 acc[4][4] = {};
  gemm_kloop(xb + m0 * 512,  512,  Wrob + n0 * 512,  512,  512,  As, Bs, acc);
  gemm_kloop(hs + m0 * 1024, 1024, Whob + n0 * 1024, 1024, 1024, As, Bs, acc);

  const int tid = threadIdx.x;
  const int l = tid & 63, w = tid >> 6;
  const int wm = (w >> 1) * 64, wn = (w & 1) * 64;
  const int lr = l & 15, quad = l >> 4;
#pragma unroll
  for (int i = 0; i < 4; ++i)
#pragma unroll
    for (int j = 0; j < 4; ++j) {
      int row = m0 + wm + i * 16 + quad * 4;
      int col = n0 + wn + j * 16 + lr;
      float bias = Wrb[col];
#pragma unroll
      for (int r = 0; r < 4; ++r)
        y[(row + r) * 1024 + col] = tanhfast(acc[i][j][r] + bias);
    }
}

// ---------------------------------------------------------------------------
// finish: h_last (bf16->f32) and c_last (f32) into d_out tail.
// ---------------------------------------------------------------------------
__global__ __launch_bounds__(256) void finish_kernel(
    const ushort* __restrict__ hfin, const float* __restrict__ cbuf,
    float* __restrict__ out_tail)
{
  int i = blockIdx.x * 256 + threadIdx.x;
  if (i < 131072) {
    out_tail[i] = b2f(hfin[i]);
    out_tail[131072 + i] = cbuf[i];
  }
}

// ---------------------------------------------------------------------------
extern "C" void kernel_launch(void* const* d_in, const int* in_sizes, int n_in,
                              void* d_out, int out_size, void* d_ws, size_t ws_size,
                              hipStream_t stream)
{
  const float* x   = (const float*)d_in[0];
  const float* xd  = (const float*)d_in[1];
  const float* hid = (const float*)d_in[2];
  const float* cel = (const float*)d_in[3];
  const float* Win[6] = {(const float*)d_in[4], (const float*)d_in[5],
                         (const float*)d_in[6], (const float*)d_in[7],
                         (const float*)d_in[8], (const float*)d_in[9]};
  const float* Whn[5] = {(const float*)d_in[10], (const float*)d_in[11],
                         (const float*)d_in[12], (const float*)d_in[13],
                         (const float*)d_in[14]};
  const float* bia[5] = {(const float*)d_in[15], (const float*)d_in[16],
                         (const float*)d_in[17], (const float*)d_in[18],
                         (const float*)d_in[19]};
  const float* Wrb = (const float*)d_in[20];
  float* y = (float*)d_out;

  // ws carve (bytes):
  char* ws = (char*)d_ws;
  ushort* xb    = (ushort*)(ws);                  //  33,554,432
  ushort* xdb   = (ushort*)(ws + 33554432);       //  33,554,432
  ushort* Wb    = (ushort*)(ws + 67108864);       //   6,291,456 (6x 1024x512)
  ushort* Whb   = (ushort*)(ws + 73400320);       //  10,485,760 (5x 1024x1024)
  ushort* hs    = (ushort*)(ws + 83886080);       //  67,108,864
  ushort* h0    = (ushort*)(ws + 150994944);      //     262,144
  ushort* h1    = (ushort*)(ws + 151257088);      //     262,144
  float*  cbuf  = (float*) (ws + 151519232);      //     524,288
  float*  bias5 = (float*) (ws + 152043520);      //      20,480
  ushort* P     = (ushort*)(ws + 152064000);      // chunk*1,310,720

  // Largest pow2 chunk (divisor of 256) whose P fits; floor at 1.
  int chunk = 1;
  for (int c = 256; c >= 1; c >>= 1)
    if (152064000ull + (unsigned long long)c * 1310720ull <= (unsigned long long)ws_size) {
      chunk = c; break;
    }
  int lc = 31 - __builtin_clz((unsigned)chunk);

  // --- conversions f32 -> bf16 ---
  cvt_kernel<<<16384, 256, 0, stream>>>(x,  xb,  16777216);
  cvt_kernel<<<16384, 256, 0, stream>>>(xd, xdb, 16777216);
  for (int i = 0; i < 6; ++i)
    cvt_kernel<<<512, 256, 0, stream>>>(Win[i], Wb + i * 524288, 524288);
  for (int i = 0; i < 5; ++i)
    cvt_kernel<<<1024, 256, 0, stream>>>(Whn[i], Whb + i * 1048576, 1048576);
  cvt_kernel<<<128, 256, 0, stream>>>(hid, h0, 131072);
  hipMemcpyAsync(cbuf, cel, 131072 * 4, hipMemcpyDeviceToDevice, stream);
  for (int i = 0; i < 5; ++i)
    hipMemcpyAsync(bias5 + i * 1024, bia[i], 4096, hipMemcpyDeviceToDevice, stream);

  // --- pipeline ---
  ushort* hb[2] = {h0, h1};
  int par = 0;
  int t = 0;
  bool coop_ok = true;
  for (int c = 0; c < 256 / chunk; ++c) {
    gemm_pre<<<dim3(chunk, 40), 256, 0, stream>>>(xb, xdb, Wb, bias5, P,
                                                  c * chunk, lc);
    if (coop_ok) {
      ushort* hAarg = hb[par];
      ushort* hBarg = hb[par ^ 1];
      int t0 = c * chunk;
      void* args[] = {&hAarg, &hBarg, &cbuf, &Whb, &P, &hs, &t0, &chunk, &lc};
      hipError_t e = hipLaunchCooperativeKernel((const void*)lstm_chunk,
                                                dim3(256), dim3(256),
                                                args, 0, stream);
      if (e == hipSuccess) {
        par ^= (chunk & 1);
        t += chunk;
        continue;
      }
      coop_ok = false;  // fall through to per-step path
    }
    for (int tt = 0; tt < chunk; ++tt, ++t) {
      lstm_step<<<dim3(4, 64), 64, 0, stream>>>(hb[par], hb[par ^ 1], cbuf,
                                                Whb, P, hs, t, tt, lc);
      par ^= 1;
    }
  }
  gemm_post<<<dim3(256, 8), 256, 0, stream>>>(xb, hs, Wb + 5 * 524288,
                                              Whb + 3 * 1048576, Wrb, y);
  finish_kernel<<<512, 256, 0, stream>>>(hb[par], cbuf, y + 33554432);
}

// Round 2
// 11466.272 us; speedup vs baseline: 1.0608x; 1.0608x over previous
//
#include <hip/hip_runtime.h>

// Problem: new_LSTM_30365418783418  (B=128, T=256, I=512, H=1024)
// R6: persistent cooperative recurrence, hand-rolled grid barrier.
//  - cg::grid.sync() measured ~38us/step (lstm_chunk 11.4ms, MfmaUtil 1.9%).
//    Replaced with per-block generation flags: release-store flags[bid]=gen,
//    thread tid polls flags[tid] (agent-scope relaxed), __threadfence acquire.
//  - Weight fragments moved to LDS (2x32KB, packed MFMA B-layout, loaded once)
//    -- VGPR_Count=108 showed the compiler was NOT keeping B0[32] in regs.
//  - P preactivations prefetched before the K-loop (latency hidden by MFMA).
//
// d_in: 0:x 1:x_d 2:hidden 3:cell | 4..9: Wii,Wif,Wig,Wio,Wid,Wro (H,I)
//       10..14: Whi,Whf,Whg,Who,Whd (H,H) | 15..20: bi,bf,bg,bo,bd,Wrb (H,)
// d_out: y(128,256,1024) ++ h_last(128,1024) ++ c_last(128,1024), float32.

using bf16x8 = __attribute__((ext_vector_type(8))) __bf16;
using f32x4  = __attribute__((ext_vector_type(4))) float;

#define MFMA16(a, b, c) __builtin_amdgcn_mfma_f32_16x16x32_bf16(a, b, c, 0, 0, 0)

static __device__ __forceinline__ float b2f(ushort u) {
  union { unsigned int i; float f; } v; v.i = ((unsigned int)u) << 16; return v.f;
}
static __device__ __forceinline__ ushort f2b(float f) {
  union { float f; unsigned int i; } v; v.f = f;
  unsigned int x = v.i;
  return (ushort)((x + 0x7fffu + ((x >> 16) & 1u)) >> 16);  // RNE
}
static __device__ __forceinline__ float sigm(float x) {
  return 1.0f / (1.0f + __expf(-x));
}
static __device__ __forceinline__ float tanhfast(float x) {
  float e = __expf(2.0f * x);          // tanh = 1 - 2/(e^{2x}+1); saturates
  return 1.0f - 2.0f / (e + 1.0f);
}

// Hand-rolled grid barrier. gridDim.x == 256, blockDim.x == 256.
// flags[bid] monotonically counts completed steps (zeroed per launch-batch).
static __device__ __forceinline__ void grid_barrier(unsigned int* flags,
                                                    unsigned int gen)
{
  __syncthreads();                       // drains each wave's vmcnt before bar
  if (threadIdx.x == 0) {
    __threadfence();                     // wbL2: publish h/hs to L3
    __hip_atomic_store(flags + blockIdx.x, gen, __ATOMIC_RELEASE,
                       __HIP_MEMORY_SCOPE_AGENT);
  }
  // thread tid watches flags[tid]; block exits when all 256 flags >= gen
  while (__hip_atomic_load(flags + threadIdx.x, __ATOMIC_RELAXED,
                           __HIP_MEMORY_SCOPE_AGENT) < gen) {
    __builtin_amdgcn_s_sleep(2);
  }
  __syncthreads();
  __threadfence();                       // invL2: acquire fresh h
}

// ---------------------------------------------------------------------------
// f32 -> bf16 conversion, 4 elems/thread. n % 4 == 0.
// ---------------------------------------------------------------------------
__global__ __launch_bounds__(256) void cvt_kernel(const float* __restrict__ src,
                                                  ushort* __restrict__ dst, int n)
{
  int i = (blockIdx.x * 256 + threadIdx.x) * 4;
  if (i < n) {
    float4 v = *(const float4*)(src + i);
    ushort4 o;
    o.x = f2b(v.x); o.y = f2b(v.y); o.z = f2b(v.z); o.w = f2b(v.w);
    *(ushort4*)(dst + i) = o;
  }
}

// ---------------------------------------------------------------------------
// Generic 128x128 NT bf16 GEMM K-loop, plain-load LDS staging.
// ---------------------------------------------------------------------------
static __device__ __forceinline__ void gemm_kloop(
    const ushort* __restrict__ A, int lda,
    const ushort* __restrict__ Bw, int ldb, int K,
    ushort* As, ushort* Bs, f32x4 (&acc)[4][4])
{
  const int tid = threadIdx.x;
  const int l = tid & 63, w = tid >> 6;
  const int wm = (w >> 1) * 64, wn = (w & 1) * 64;
  const int lr = l & 15, quad = l >> 4;
  bf16x8* Asv = (bf16x8*)As;
  bf16x8* Bsv = (bf16x8*)Bs;
  for (int k0 = 0; k0 < K; k0 += 32) {
    __syncthreads();
#pragma unroll
    for (int it = 0; it < 2; ++it) {
      int c = it * 256 + tid;
      int row = c >> 2, seg = c & 3;
      Asv[c] = *(const bf16x8*)(A  + row * lda + k0 + seg * 8);
      Bsv[c] = *(const bf16x8*)(Bw + row * ldb + k0 + seg * 8);
    }
    __syncthreads();
    bf16x8 af[4], bfr[4];
#pragma unroll
    for (int i = 0; i < 4; ++i) af[i]  = Asv[(wm + i * 16 + lr) * 4 + quad];
#pragma unroll
    for (int j = 0; j < 4; ++j) bfr[j] = Bsv[(wn + j * 16 + lr) * 4 + quad];
#pragma unroll
    for (int i = 0; i < 4; ++i)
#pragma unroll
      for (int j = 0; j < 4; ++j)
        acc[i][j] = MFMA16(af[i], bfr[j], acc[i][j]);
  }
}

// ---------------------------------------------------------------------------
// Kernel 1 (per chunk): P[m'][g*1024+h] = bf16( A[b, t0+tt] . Wg[h] + bias )
// m' = b*chunk + tt. Grid (chunk, 40), 256 threads.
// ---------------------------------------------------------------------------
__global__ __launch_bounds__(256) void gemm_pre(
    const ushort* __restrict__ xb, const ushort* __restrict__ xdb,
    const ushort* __restrict__ Wb,      // 6x(1024x512) contiguous (Wii..Wid,Wro)
    const float* __restrict__ bias5, ushort* __restrict__ P,
    int t0, int lc)
{
  __shared__ __align__(16) ushort As[4096], Bs[4096];
  const int m0 = blockIdx.x * 128;
  const int n0 = blockIdx.y * 128;
  const int g = n0 >> 10;
  const ushort* A = (g == 4) ? xdb : xb;
  const ushort* Bw = Wb + g * 524288 + (n0 & 1023) * 512;
  const int cm1 = (1 << lc) - 1;

  const int tid = threadIdx.x;
  const int l = tid & 63, w = tid >> 6;
  const int wm = (w >> 1) * 64, wn = (w & 1) * 64;
  const int lr = l & 15, quad = l >> 4;
  f32x4 acc[4][4] = {};
  bf16x8* Asv = (bf16x8*)As;
  bf16x8* Bsv = (bf16x8*)Bs;

  for (int k0 = 0; k0 < 512; k0 += 32) {
    __syncthreads();
#pragma unroll
    for (int it = 0; it < 2; ++it) {
      int c = it * 256 + tid;
      int row = c >> 2, seg = c & 3;
      int gr = m0 + row;                              // m' row
      int arow = ((gr >> lc) << 8) + t0 + (gr & cm1); // b*T + t
      Asv[c] = *(const bf16x8*)(A  + arow * 512 + k0 + seg * 8);
      Bsv[c] = *(const bf16x8*)(Bw + row  * 512 + k0 + seg * 8);
    }
    __syncthreads();
    bf16x8 af[4], bfr[4];
#pragma unroll
    for (int i = 0; i < 4; ++i) af[i]  = Asv[(wm + i * 16 + lr) * 4 + quad];
#pragma unroll
    for (int j = 0; j < 4; ++j) bfr[j] = Bsv[(wn + j * 16 + lr) * 4 + quad];
#pragma unroll
    for (int i = 0; i < 4; ++i)
#pragma unroll
      for (int j = 0; j < 4; ++j)
        acc[i][j] = MFMA16(af[i], bfr[j], acc[i][j]);
  }

#pragma unroll
  for (int i = 0; i < 4; ++i)
#pragma unroll
    for (int j = 0; j < 4; ++j) {
      int row = m0 + wm + i * 16 + quad * 4;   // C/D: row = quad*4+reg (m89)
      int col = n0 + wn + j * 16 + lr;         //      col = lane&15
      float bias = bias5[col];
#pragma unroll
      for (int r = 0; r < 4; ++r)
        P[(row + r) * 5120 + col] = f2b(acc[i][j][r] + bias);
    }
}

// ---------------------------------------------------------------------------
// R6 persistent recurrent kernel (cooperative). Grid 256 x 256 threads.
// Block nb owns h-cols nb*4..+3, all 5 gates (20 Whb rows):
//   local n = lr: gates 0..3 x hc 0..3  -> Bs0 fragments (LDS, 32KB)
//   gate 4 x hc 0..3 (rows 16..19, pad) -> Bs1 fragments (LDS, 32KB)
// Per step: C[128 x 32] = h @ Wslice^T, wave w owns batch rows w*32..w*32+31.
// ---------------------------------------------------------------------------
__global__ __launch_bounds__(256, 1) void lstm_chunk(
    ushort* __restrict__ hA, ushort* __restrict__ hB,
    float* __restrict__ cbuf, const ushort* __restrict__ Whb,
    const ushort* __restrict__ P, ushort* __restrict__ hs,
    unsigned int* __restrict__ flags, int t0, int nt, int lc)
{
  __shared__ __align__(16) ushort Bs0[32 * 64 * 8];   // 32KB gates i,f,g,o
  __shared__ __align__(16) ushort Bs1[32 * 64 * 8];   // 32KB gate d (+zeros)
  __shared__ float Pls[128 * 21];                     // preacts, pad 21
  __shared__ float cs[128 * 5];                       // cell slice, pad 5

  const int tid = threadIdx.x;
  const int l = tid & 63, w = tid >> 6;
  const int lr = l & 15, quad = l >> 4;
  const int nb = blockIdx.x;                          // 0..255

  // ---- Bs0 fragments: local n = lr (gate lr>>2, hc lr&3), once ----
  {
    const ushort* wp = Whb + (((lr >> 2) << 10) + nb * 4 + (lr & 3)) * 1024 + quad * 8;
#pragma unroll
    for (int kk = 0; kk < 8; ++kk) {
      int k = w * 8 + kk;
      *(bf16x8*)(Bs0 + (k * 64 + l) * 8) = *(const bf16x8*)(wp + k * 32);
    }
  }
  // ---- Bs1 fragments: gate 4 on lanes lr<4, zero elsewhere ----
  {
    const ushort* wp = Whb + (4096 + nb * 4 + (lr & 3)) * 1024 + quad * 8;
#pragma unroll
    for (int kk = 0; kk < 8; ++kk) {
      int k = w * 8 + kk;
      bf16x8 v = {};
      if (lr < 4) v = *(const bf16x8*)(wp + k * 32);
      *(bf16x8*)(Bs1 + (k * 64 + l) * 8) = v;
    }
  }
  // ---- cell slice -> LDS ----
  if (tid < 128) {
    float4 cv = *(const float4*)(cbuf + tid * 1024 + nb * 4);
    cs[tid * 5 + 0] = cv.x; cs[tid * 5 + 1] = cv.y;
    cs[tid * 5 + 2] = cv.z; cs[tid * 5 + 3] = cv.w;
  }
  __syncthreads();

  const int aoff = (w * 32 + lr) * 1024 + quad * 8;
  const bf16x8* B0v = (const bf16x8*)Bs0;
  const bf16x8* B1v = (const bf16x8*)Bs1;

  for (int tt = 0; tt < nt; ++tt) {
    const ushort* hr = (tt & 1) ? hB : hA;
    ushort* hw       = (tt & 1) ? hA : hB;

    // ---- prefetch this step's P (independent of h; hides under MFMA) ----
    ushort4 p0, p1, p2, p3, p4;
    if (tid < 128) {
      const int prow = ((tid << lc) + tt) * 5120 + nb * 4;
      p0 = *(const ushort4*)(P + prow);
      p1 = *(const ushort4*)(P + prow + 1024);
      p2 = *(const ushort4*)(P + prow + 2048);
      p3 = *(const ushort4*)(P + prow + 3072);
      p4 = *(const ushort4*)(P + prow + 4096);
    }

    f32x4 acc[2][2] = {};
#pragma unroll
    for (int k = 0; k < 32; ++k) {
      bf16x8 a0 = *(const bf16x8*)(hr + aoff + k * 32);
      bf16x8 a1 = *(const bf16x8*)(hr + aoff + 16384 + k * 32);
      bf16x8 b0 = B0v[k * 64 + l];
      bf16x8 b1 = B1v[k * 64 + l];
      acc[0][0] = MFMA16(a0, b0, acc[0][0]);
      acc[1][0] = MFMA16(a1, b0, acc[1][0]);
      acc[0][1] = MFMA16(a0, b1, acc[0][1]);
      acc[1][1] = MFMA16(a1, b1, acc[1][1]);
    }

    // C/D mapping (m89): row = quad*4+reg, col = lane&15
#pragma unroll
    for (int i = 0; i < 2; ++i) {
      int b = w * 32 + i * 16 + quad * 4;
#pragma unroll
      for (int r = 0; r < 4; ++r)
        Pls[(b + r) * 21 + lr] = acc[i][0][r];
      if (lr < 4) {
#pragma unroll
        for (int r = 0; r < 4; ++r)
          Pls[(b + r) * 21 + 16 + lr] = acc[i][1][r];
      }
    }
    __syncthreads();

    if (tid < 128) {
      const int b = tid;
      const float* pr = Pls + b * 21;
      ushort hv0, hv1, hv2, hv3;
#pragma unroll
      for (int hc = 0; hc < 4; ++hc) {
        float pi = b2f(((const ushort*)&p0)[hc]) + pr[0 + hc];
        float pf = b2f(((const ushort*)&p1)[hc]) + pr[4 + hc];
        float pg = b2f(((const ushort*)&p2)[hc]) + pr[8 + hc];
        float po = b2f(((const ushort*)&p3)[hc]) + pr[12 + hc];
        float pd = b2f(((const ushort*)&p4)[hc]) + pr[16 + hc];
        float ig = sigm(pi), fg = sigm(pf), gg = tanhfast(pg);
        float og = sigm(po), dg = sigm(pd);
        float cnew = fg * cs[b * 5 + hc] + ig * gg + dg;
        cs[b * 5 + hc] = cnew;
        ushort hb16 = f2b(og * tanhfast(cnew));
        if (hc == 0) hv0 = hb16; else if (hc == 1) hv1 = hb16;
        else if (hc == 2) hv2 = hb16; else hv3 = hb16;
      }
      ushort4 hvv; hvv.x = hv0; hvv.y = hv1; hvv.z = hv2; hvv.w = hv3;
      *(ushort4*)(hw + b * 1024 + nb * 4) = hvv;
      *(ushort4*)(hs + (b * 256 + t0 + tt) * 1024 + nb * 4) = hvv;
    }

    if (tt + 1 < nt)
      grid_barrier(flags, (unsigned int)(t0 + tt + 1));
    else
      __syncthreads();   // protect cs before writeback; kernel end flushes mem
  }

  // ---- cell slice back to global ----
  if (tid < 128) {
    float4 cv;
    cv.x = cs[tid * 5 + 0]; cv.y = cs[tid * 5 + 1];
    cv.z = cs[tid * 5 + 2]; cv.w = cs[tid * 5 + 3];
    *(float4*)(cbuf + tid * 1024 + nb * 4) = cv;
  }
}

// ---------------------------------------------------------------------------
// Fallback kernel (x256): one LSTM step. Grid (4,64) x 64 threads.
// ---------------------------------------------------------------------------
__global__ __launch_bounds__(64) void lstm_step(
    const ushort* __restrict__ hprev, ushort* __restrict__ hnext,
    float* __restrict__ cbuf, const ushort* __restrict__ Whb,
    const ushort* __restrict__ P, ushort* __restrict__ hs,
    int t, int tloc, int lc)
{
  const int l = threadIdx.x;
  const int m0 = blockIdx.x * 32;
  const int hc = blockIdx.y * 16;
  const int lr = l & 15, quad = l >> 4;

  f32x4 acc[2][5] = {};
  const ushort* a0p = hprev + (m0 + lr) * 1024 + quad * 8;
  const ushort* a1p = a0p + 16 * 1024;
  const ushort* wp = Whb + (hc + lr) * 1024 + quad * 8;

#pragma unroll 2
  for (int k0 = 0; k0 < 1024; k0 += 32) {
    bf16x8 a0 = *(const bf16x8*)(a0p + k0);
    bf16x8 a1 = *(const bf16x8*)(a1p + k0);
    bf16x8 b0 = *(const bf16x8*)(wp + k0);
    bf16x8 b1 = *(const bf16x8*)(wp + 1048576 + k0);
    bf16x8 b2 = *(const bf16x8*)(wp + 2097152 + k0);
    bf16x8 b3 = *(const bf16x8*)(wp + 3145728 + k0);
    bf16x8 b4 = *(const bf16x8*)(wp + 4194304 + k0);
    acc[0][0] = MFMA16(a0, b0, acc[0][0]);
    acc[1][0] = MFMA16(a1, b0, acc[1][0]);
    acc[0][1] = MFMA16(a0, b1, acc[0][1]);
    acc[1][1] = MFMA16(a1, b1, acc[1][1]);
    acc[0][2] = MFMA16(a0, b2, acc[0][2]);
    acc[1][2] = MFMA16(a1, b2, acc[1][2]);
    acc[0][3] = MFMA16(a0, b3, acc[0][3]);
    acc[1][3] = MFMA16(a1, b3, acc[1][3]);
    acc[0][4] = MFMA16(a0, b4, acc[0][4]);
    acc[1][4] = MFMA16(a1, b4, acc[1][4]);
  }

  const int h = hc + lr;
#pragma unroll
  for (int i = 0; i < 2; ++i) {
#pragma unroll
    for (int r = 0; r < 4; ++r) {
      int b = m0 + i * 16 + quad * 4 + r;
      int prow = ((b << lc) + tloc) * 5120;
      float pi = b2f(P[prow + h])          + acc[i][0][r];
      float pf = b2f(P[prow + 1024 + h])   + acc[i][1][r];
      float pg = b2f(P[prow + 2048 + h])   + acc[i][2][r];
      float po = b2f(P[prow + 3072 + h])   + acc[i][3][r];
      float pd = b2f(P[prow + 4096 + h])   + acc[i][4][r];
      float ig = sigm(pi), fg = sigm(pf), gg = tanhfast(pg);
      float og = sigm(po), dg = sigm(pd);
      float cold = cbuf[b * 1024 + h];
      float cnew = fg * cold + ig * gg + dg;
      cbuf[b * 1024 + h] = cnew;
      ushort hb = f2b(og * tanhfast(cnew));
      hnext[b * 1024 + h] = hb;
      hs[(b * 256 + t) * 1024 + h] = hb;
    }
  }
}

// ---------------------------------------------------------------------------
// Kernel 3: y = tanh(x@Wro^T + hs@Who^T + Wrb), f32 out. Grid (256, 8).
// ---------------------------------------------------------------------------
__global__ __launch_bounds__(256) void gemm_post(
    const ushort* __restrict__ xb, const ushort* __restrict__ hs,
    const ushort* __restrict__ Wrob, const ushort* __restrict__ Whob,
    const float* __restrict__ Wrb, float* __restrict__ y)
{
  __shared__ __align__(16) ushort As[4096], Bs[4096];
  const int m0 = blockIdx.x * 128;
  const int n0 = blockIdx.y * 128;
  f32x4 acc[4][4] = {};
  gemm_kloop(xb + m0 * 512,  512,  Wrob + n0 * 512,  512,  512,  As, Bs, acc);
  gemm_kloop(hs + m0 * 1024, 1024, Whob + n0 * 1024, 1024, 1024, As, Bs, acc);

  const int tid = threadIdx.x;
  const int l = tid & 63, w = tid >> 6;
  const int wm = (w >> 1) * 64, wn = (w & 1) * 64;
  const int lr = l & 15, quad = l >> 4;
#pragma unroll
  for (int i = 0; i < 4; ++i)
#pragma unroll
    for (int j = 0; j < 4; ++j) {
      int row = m0 + wm + i * 16 + quad * 4;
      int col = n0 + wn + j * 16 + lr;
      float bias = Wrb[col];
#pragma unroll
      for (int r = 0; r < 4; ++r)
        y[(row + r) * 1024 + col] = tanhfast(acc[i][j][r] + bias);
    }
}

// ---------------------------------------------------------------------------
// finish: h_last (bf16->f32) and c_last (f32) into d_out tail.
// ---------------------------------------------------------------------------
__global__ __launch_bounds__(256) void finish_kernel(
    const ushort* __restrict__ hfin, const float* __restrict__ cbuf,
    float* __restrict__ out_tail)
{
  int i = blockIdx.x * 256 + threadIdx.x;
  if (i < 131072) {
    out_tail[i] = b2f(hfin[i]);
    out_tail[131072 + i] = cbuf[i];
  }
}

// ---------------------------------------------------------------------------
extern "C" void kernel_launch(void* const* d_in, const int* in_sizes, int n_in,
                              void* d_out, int out_size, void* d_ws, size_t ws_size,
                              hipStream_t stream)
{
  const float* x   = (const float*)d_in[0];
  const float* xd  = (const float*)d_in[1];
  const float* hid = (const float*)d_in[2];
  const float* cel = (const float*)d_in[3];
  const float* Win[6] = {(const float*)d_in[4], (const float*)d_in[5],
                         (const float*)d_in[6], (const float*)d_in[7],
                         (const float*)d_in[8], (const float*)d_in[9]};
  const float* Whn[5] = {(const float*)d_in[10], (const float*)d_in[11],
                         (const float*)d_in[12], (const float*)d_in[13],
                         (const float*)d_in[14]};
  const float* bia[5] = {(const float*)d_in[15], (const float*)d_in[16],
                         (const float*)d_in[17], (const float*)d_in[18],
                         (const float*)d_in[19]};
  const float* Wrb = (const float*)d_in[20];
  float* y = (float*)d_out;

  // ws carve (bytes):
  char* ws = (char*)d_ws;
  ushort* xb    = (ushort*)(ws);                  //  33,554,432
  ushort* xdb   = (ushort*)(ws + 33554432);       //  33,554,432
  ushort* Wb    = (ushort*)(ws + 67108864);       //   6,291,456 (6x 1024x512)
  ushort* Whb   = (ushort*)(ws + 73400320);       //  10,485,760 (5x 1024x1024)
  ushort* hs    = (ushort*)(ws + 83886080);       //  67,108,864
  ushort* h0    = (ushort*)(ws + 150994944);      //     262,144
  ushort* h1    = (ushort*)(ws + 151257088);      //     262,144
  float*  cbuf  = (float*) (ws + 151519232);      //     524,288
  float*  bias5 = (float*) (ws + 152043520);      //      20,480
  unsigned int* flags = (unsigned int*)(ws + 152064000);  // 4,096 (barrier)
  ushort* P     = (ushort*)(ws + 152068096);      // chunk*1,310,720

  // Largest pow2 chunk (divisor of 256) whose P fits; floor at 1.
  int chunk = 1;
  for (int c = 256; c >= 1; c >>= 1)
    if (152068096ull + (unsigned long long)c * 1310720ull <= (unsigned long long)ws_size) {
      chunk = c; break;
    }
  int lc = 31 - __builtin_clz((unsigned)chunk);

  // --- conversions f32 -> bf16 ---
  cvt_kernel<<<16384, 256, 0, stream>>>(x,  xb,  16777216);
  cvt_kernel<<<16384, 256, 0, stream>>>(xd, xdb, 16777216);
  for (int i = 0; i < 6; ++i)
    cvt_kernel<<<512, 256, 0, stream>>>(Win[i], Wb + i * 524288, 524288);
  for (int i = 0; i < 5; ++i)
    cvt_kernel<<<1024, 256, 0, stream>>>(Whn[i], Whb + i * 1048576, 1048576);
  cvt_kernel<<<128, 256, 0, stream>>>(hid, h0, 131072);
  hipMemcpyAsync(cbuf, cel, 131072 * 4, hipMemcpyDeviceToDevice, stream);
  for (int i = 0; i < 5; ++i)
    hipMemcpyAsync(bias5 + i * 1024, bia[i], 4096, hipMemcpyDeviceToDevice, stream);
  hipMemsetAsync(flags, 0, 4096, stream);   // reset barrier generations per run

  // --- pipeline ---
  ushort* hb[2] = {h0, h1};
  int par = 0;
  int t = 0;
  bool coop_ok = true;
  for (int c = 0; c < 256 / chunk; ++c) {
    gemm_pre<<<dim3(chunk, 40), 256, 0, stream>>>(xb, xdb, Wb, bias5, P,
                                                  c * chunk, lc);
    if (coop_ok) {
      ushort* hAarg = hb[par];
      ushort* hBarg = hb[par ^ 1];
      int t0 = c * chunk;
      void* args[] = {&hAarg, &hBarg, &cbuf, &Whb, &P, &hs, &flags,
                      &t0, &chunk, &lc};
      hipError_t e = hipLaunchCooperativeKernel((const void*)lstm_chunk,
                                                dim3(256), dim3(256),
                                                args, 0, stream);
      if (e == hipSuccess) {
        par ^= (chunk & 1);
        t += chunk;
        continue;
      }
      coop_ok = false;  // fall through to per-step path
    }
    for (int tt = 0; tt < chunk; ++tt, ++t) {
      lstm_step<<<dim3(4, 64), 64, 0, stream>>>(hb[par], hb[par ^ 1], cbuf,
                                                Whb, P, hs, t, tt, lc);
      par ^= 1;
    }
  }
  gemm_post<<<dim3(256, 8), 256, 0, stream>>>(xb, hs, Wb + 5 * 524288,
                                              Whb + 3 * 1048576, Wrb, y);
  finish_kernel<<<512, 256, 0, stream>>>(hb[par], cbuf, y + 33554432);
}

// Round 3
// 4804.440 us; speedup vs baseline: 2.5316x; 2.3866x over previous
//
#include <hip/hip_runtime.h>

// Problem: new_LSTM_30365418783418  (B=128, T=256, I=512, H=1024)
// R7: fence-free persistent recurrence.
//  - R5 (cg.sync, 44.5us/step) vs R6 (flag barrier + __threadfence, 41.5us/step)
//    isolates the cost to the agent-scope FENCES (buffer_wbl2/buffer_inv L2
//    walks), not the rendezvous. This round removes all fences:
//    * h written via agent-scope RELAXED atomic b64 stores (sc1 write-through
//      to L3, vmcnt-tracked; __syncthreads' vmcnt(0) drain = release).
//    * h read via PLAIN CACHED loads from per-step-unique addresses (hs[t-1])
//      -- written-once/read-once lines can't be stale, so no buffer_inv; L2
//      serves the 32-blocks-per-XCD broadcast.
//    * flags relaxed agent atomics only; asm "memory" stops load hoisting.
//  - hA/hB ping-pong eliminated (address reuse was what required coherence).
//
// d_in: 0:x 1:x_d 2:hidden 3:cell | 4..9: Wii,Wif,Wig,Wio,Wid,Wro (H,I)
//       10..14: Whi,Whf,Whg,Who,Whd (H,H) | 15..20: bi,bf,bg,bo,bd,Wrb (H,)
// d_out: y(128,256,1024) ++ h_last(128,1024) ++ c_last(128,1024), float32.

using bf16x8 = __attribute__((ext_vector_type(8))) __bf16;
using f32x4  = __attribute__((ext_vector_type(4))) float;

#define MFMA16(a, b, c) __builtin_amdgcn_mfma_f32_16x16x32_bf16(a, b, c, 0, 0, 0)

static __device__ __forceinline__ float b2f(ushort u) {
  union { unsigned int i; float f; } v; v.i = ((unsigned int)u) << 16; return v.f;
}
static __device__ __forceinline__ ushort f2b(float f) {
  union { float f; unsigned int i; } v; v.f = f;
  unsigned int x = v.i;
  return (ushort)((x + 0x7fffu + ((x >> 16) & 1u)) >> 16);  // RNE
}
static __device__ __forceinline__ float sigm(float x) {
  return 1.0f / (1.0f + __expf(-x));
}
static __device__ __forceinline__ float tanhfast(float x) {
  float e = __expf(2.0f * x);          // tanh = 1 - 2/(e^{2x}+1); saturates
  return 1.0f - 2.0f / (e + 1.0f);
}

// Fence-free grid barrier. gridDim.x == 256 == blockDim.x.
// Relies on: __syncthreads() emits s_waitcnt vmcnt(0) (drains this wave's
// sc1 h-stores to L3) before s_barrier; flag ops are relaxed agent atomics
// (no buffer_wbl2/buffer_inv codegen).
static __device__ __forceinline__ void grid_barrier(unsigned int* flags,
                                                    unsigned int gen)
{
  __syncthreads();
  if (threadIdx.x == 0) {
    asm volatile("s_waitcnt vmcnt(0)" ::: "memory");
    __hip_atomic_store(flags + blockIdx.x, gen, __ATOMIC_RELAXED,
                       __HIP_MEMORY_SCOPE_AGENT);
  }
  while (__hip_atomic_load(flags + threadIdx.x, __ATOMIC_RELAXED,
                           __HIP_MEMORY_SCOPE_AGENT) < gen) {
    __builtin_amdgcn_s_sleep(1);
  }
  asm volatile("" ::: "memory");       // no load hoisting above the poll
  __syncthreads();
}

// ---------------------------------------------------------------------------
// f32 -> bf16 conversion, 4 elems/thread. n % 4 == 0.
// ---------------------------------------------------------------------------
__global__ __launch_bounds__(256) void cvt_kernel(const float* __restrict__ src,
                                                  ushort* __restrict__ dst, int n)
{
  int i = (blockIdx.x * 256 + threadIdx.x) * 4;
  if (i < n) {
    float4 v = *(const float4*)(src + i);
    ushort4 o;
    o.x = f2b(v.x); o.y = f2b(v.y); o.z = f2b(v.z); o.w = f2b(v.w);
    *(ushort4*)(dst + i) = o;
  }
}

// ---------------------------------------------------------------------------
// Generic 128x128 NT bf16 GEMM K-loop, plain-load LDS staging.
// ---------------------------------------------------------------------------
static __device__ __forceinline__ void gemm_kloop(
    const ushort* __restrict__ A, int lda,
    const ushort* __restrict__ Bw, int ldb, int K,
    ushort* As, ushort* Bs, f32x4 (&acc)[4][4])
{
  const int tid = threadIdx.x;
  const int l = tid & 63, w = tid >> 6;
  const int wm = (w >> 1) * 64, wn = (w & 1) * 64;
  const int lr = l & 15, quad = l >> 4;
  bf16x8* Asv = (bf16x8*)As;
  bf16x8* Bsv = (bf16x8*)Bs;
  for (int k0 = 0; k0 < K; k0 += 32) {
    __syncthreads();
#pragma unroll
    for (int it = 0; it < 2; ++it) {
      int c = it * 256 + tid;
      int row = c >> 2, seg = c & 3;
      Asv[c] = *(const bf16x8*)(A  + row * lda + k0 + seg * 8);
      Bsv[c] = *(const bf16x8*)(Bw + row * ldb + k0 + seg * 8);
    }
    __syncthreads();
    bf16x8 af[4], bfr[4];
#pragma unroll
    for (int i = 0; i < 4; ++i) af[i]  = Asv[(wm + i * 16 + lr) * 4 + quad];
#pragma unroll
    for (int j = 0; j < 4; ++j) bfr[j] = Bsv[(wn + j * 16 + lr) * 4 + quad];
#pragma unroll
    for (int i = 0; i < 4; ++i)
#pragma unroll
      for (int j = 0; j < 4; ++j)
        acc[i][j] = MFMA16(af[i], bfr[j], acc[i][j]);
  }
}

// ---------------------------------------------------------------------------
// Kernel 1 (per chunk): P[m'][g*1024+h] = bf16( A[b, t0+tt] . Wg[h] + bias )
// m' = b*chunk + tt. Grid (chunk, 40), 256 threads.
// ---------------------------------------------------------------------------
__global__ __launch_bounds__(256) void gemm_pre(
    const ushort* __restrict__ xb, const ushort* __restrict__ xdb,
    const ushort* __restrict__ Wb,      // 6x(1024x512) contiguous (Wii..Wid,Wro)
    const float* __restrict__ bias5, ushort* __restrict__ P,
    int t0, int lc)
{
  __shared__ __align__(16) ushort As[4096], Bs[4096];
  const int m0 = blockIdx.x * 128;
  const int n0 = blockIdx.y * 128;
  const int g = n0 >> 10;
  const ushort* A = (g == 4) ? xdb : xb;
  const ushort* Bw = Wb + g * 524288 + (n0 & 1023) * 512;
  const int cm1 = (1 << lc) - 1;

  const int tid = threadIdx.x;
  const int l = tid & 63, w = tid >> 6;
  const int wm = (w >> 1) * 64, wn = (w & 1) * 64;
  const int lr = l & 15, quad = l >> 4;
  f32x4 acc[4][4] = {};
  bf16x8* Asv = (bf16x8*)As;
  bf16x8* Bsv = (bf16x8*)Bs;

  for (int k0 = 0; k0 < 512; k0 += 32) {
    __syncthreads();
#pragma unroll
    for (int it = 0; it < 2; ++it) {
      int c = it * 256 + tid;
      int row = c >> 2, seg = c & 3;
      int gr = m0 + row;                              // m' row
      int arow = ((gr >> lc) << 8) + t0 + (gr & cm1); // b*T + t
      Asv[c] = *(const bf16x8*)(A  + arow * 512 + k0 + seg * 8);
      Bsv[c] = *(const bf16x8*)(Bw + row  * 512 + k0 + seg * 8);
    }
    __syncthreads();
    bf16x8 af[4], bfr[4];
#pragma unroll
    for (int i = 0; i < 4; ++i) af[i]  = Asv[(wm + i * 16 + lr) * 4 + quad];
#pragma unroll
    for (int j = 0; j < 4; ++j) bfr[j] = Bsv[(wn + j * 16 + lr) * 4 + quad];
#pragma unroll
    for (int i = 0; i < 4; ++i)
#pragma unroll
      for (int j = 0; j < 4; ++j)
        acc[i][j] = MFMA16(af[i], bfr[j], acc[i][j]);
  }

#pragma unroll
  for (int i = 0; i < 4; ++i)
#pragma unroll
    for (int j = 0; j < 4; ++j) {
      int row = m0 + wm + i * 16 + quad * 4;   // C/D: row = quad*4+reg (m89)
      int col = n0 + wn + j * 16 + lr;         //      col = lane&15
      float bias = bias5[col];
#pragma unroll
      for (int r = 0; r < 4; ++r)
        P[(row + r) * 5120 + col] = f2b(acc[i][j][r] + bias);
    }
}

// ---------------------------------------------------------------------------
// R7 persistent recurrent kernel (cooperative). Grid 256 x 256 threads.
// Block nb owns h-cols nb*4..+3, all 5 gates. Weights in LDS (loaded once).
// h_{t-1} read from hs (per-step-unique addresses, plain cached loads);
// h_t written to hs via agent-scope relaxed atomic b64 (sc1 write-through).
// ---------------------------------------------------------------------------
__global__ __launch_bounds__(256, 1) void lstm_chunk(
    const ushort* __restrict__ h0,
    float* __restrict__ cbuf, const ushort* __restrict__ Whb,
    const ushort* __restrict__ P, ushort* __restrict__ hs,
    unsigned int* __restrict__ flags, int t0, int nt, int lc)
{
  __shared__ __align__(16) ushort Bs0[32 * 64 * 8];   // 32KB gates i,f,g,o
  __shared__ __align__(16) ushort Bs1[32 * 64 * 8];   // 32KB gate d (+zeros)
  __shared__ float Pls[128 * 21];                     // preacts, pad 21
  __shared__ float cs[128 * 5];                       // cell slice, pad 5

  const int tid = threadIdx.x;
  const int l = tid & 63, w = tid >> 6;
  const int lr = l & 15, quad = l >> 4;
  const int nb = blockIdx.x;                          // 0..255

  // ---- Bs0 fragments: local n = lr (gate lr>>2, hc lr&3), once ----
  {
    const ushort* wp = Whb + (((lr >> 2) << 10) + nb * 4 + (lr & 3)) * 1024 + quad * 8;
#pragma unroll
    for (int kk = 0; kk < 8; ++kk) {
      int k = w * 8 + kk;
      *(bf16x8*)(Bs0 + (k * 64 + l) * 8) = *(const bf16x8*)(wp + k * 32);
    }
  }
  // ---- Bs1 fragments: gate 4 on lanes lr<4, zero elsewhere ----
  {
    const ushort* wp = Whb + (4096 + nb * 4 + (lr & 3)) * 1024 + quad * 8;
#pragma unroll
    for (int kk = 0; kk < 8; ++kk) {
      int k = w * 8 + kk;
      bf16x8 v = {};
      if (lr < 4) v = *(const bf16x8*)(wp + k * 32);
      *(bf16x8*)(Bs1 + (k * 64 + l) * 8) = v;
    }
  }
  // ---- cell slice -> LDS ----
  if (tid < 128) {
    float4 cv = *(const float4*)(cbuf + tid * 1024 + nb * 4);
    cs[tid * 5 + 0] = cv.x; cs[tid * 5 + 1] = cv.y;
    cs[tid * 5 + 2] = cv.z; cs[tid * 5 + 3] = cv.w;
  }
  __syncthreads();

  const bf16x8* B0v = (const bf16x8*)Bs0;
  const bf16x8* B1v = (const bf16x8*)Bs1;

  for (int tt = 0; tt < nt; ++tt) {
    const int t = t0 + tt;
    // h_{t-1} source: initial h0 (stride 1024) or hs row t-1 (stride 256*1024)
    const ushort* base;
    int rs;
    if (t == 0) { base = h0;                 rs = 1024;   }
    else        { base = hs + (t - 1) * 1024; rs = 262144; }
    const ushort* a0p = base + (w * 32 + lr) * rs + quad * 8;
    const ushort* a1p = a0p + 16 * rs;

    // ---- prefetch this step's P (independent of h; hides under MFMA) ----
    ushort4 p0, p1, p2, p3, p4;
    if (tid < 128) {
      const int prow = ((tid << lc) + tt) * 5120 + nb * 4;
      p0 = *(const ushort4*)(P + prow);
      p1 = *(const ushort4*)(P + prow + 1024);
      p2 = *(const ushort4*)(P + prow + 2048);
      p3 = *(const ushort4*)(P + prow + 3072);
      p4 = *(const ushort4*)(P + prow + 4096);
    }

    f32x4 acc[2][2] = {};
#pragma unroll
    for (int k = 0; k < 32; ++k) {
      bf16x8 a0 = *(const bf16x8*)(a0p + k * 32);
      bf16x8 a1 = *(const bf16x8*)(a1p + k * 32);
      bf16x8 b0 = B0v[k * 64 + l];
      bf16x8 b1 = B1v[k * 64 + l];
      acc[0][0] = MFMA16(a0, b0, acc[0][0]);
      acc[1][0] = MFMA16(a1, b0, acc[1][0]);
      acc[0][1] = MFMA16(a0, b1, acc[0][1]);
      acc[1][1] = MFMA16(a1, b1, acc[1][1]);
    }

    // C/D mapping (m89): row = quad*4+reg, col = lane&15
#pragma unroll
    for (int i = 0; i < 2; ++i) {
      int b = w * 32 + i * 16 + quad * 4;
#pragma unroll
      for (int r = 0; r < 4; ++r)
        Pls[(b + r) * 21 + lr] = acc[i][0][r];
      if (lr < 4) {
#pragma unroll
        for (int r = 0; r < 4; ++r)
          Pls[(b + r) * 21 + 16 + lr] = acc[i][1][r];
      }
    }
    __syncthreads();

    if (tid < 128) {
      const int b = tid;
      const float* pr = Pls + b * 21;
      ushort hv0, hv1, hv2, hv3;
#pragma unroll
      for (int hc = 0; hc < 4; ++hc) {
        float pi = b2f(((const ushort*)&p0)[hc]) + pr[0 + hc];
        float pf = b2f(((const ushort*)&p1)[hc]) + pr[4 + hc];
        float pg = b2f(((const ushort*)&p2)[hc]) + pr[8 + hc];
        float po = b2f(((const ushort*)&p3)[hc]) + pr[12 + hc];
        float pd = b2f(((const ushort*)&p4)[hc]) + pr[16 + hc];
        float ig = sigm(pi), fg = sigm(pf), gg = tanhfast(pg);
        float og = sigm(po), dg = sigm(pd);
        float cnew = fg * cs[b * 5 + hc] + ig * gg + dg;
        cs[b * 5 + hc] = cnew;
        ushort hb16 = f2b(og * tanhfast(cnew));
        if (hc == 0) hv0 = hb16; else if (hc == 1) hv1 = hb16;
        else if (hc == 2) hv2 = hb16; else hv3 = hb16;
      }
      union { ushort4 s; unsigned long long u; } hu;
      hu.s.x = hv0; hu.s.y = hv1; hu.s.z = hv2; hu.s.w = hv3;
      // agent-scope write-through (sc1): visible at L3 once vmcnt drains
      __hip_atomic_store((unsigned long long*)(hs + (b * 256 + t) * 1024 + nb * 4),
                         hu.u, __ATOMIC_RELAXED, __HIP_MEMORY_SCOPE_AGENT);
    }

    if (tt + 1 < nt)
      grid_barrier(flags, (unsigned int)(t + 1));
  }

  // ---- cell slice back to global (same threads wrote cs; no sync needed) ----
  if (tid < 128) {
    float4 cv;
    cv.x = cs[tid * 5 + 0]; cv.y = cs[tid * 5 + 1];
    cv.z = cs[tid * 5 + 2]; cv.w = cs[tid * 5 + 3];
    *(float4*)(cbuf + tid * 1024 + nb * 4) = cv;
  }
}

// ---------------------------------------------------------------------------
// Fallback kernel (x256): one LSTM step. Grid (4,64) x 64 threads.
// Reads h_{t-1} from hs (or h0 at t=0); writes hs only. Per-step dispatch
// boundaries provide coherence (no atomics needed).
// ---------------------------------------------------------------------------
__global__ __launch_bounds__(64) void lstm_step(
    const ushort* __restrict__ h0, float* __restrict__ cbuf,
    const ushort* __restrict__ Whb, const ushort* __restrict__ P,
    ushort* __restrict__ hs, int t, int tloc, int lc)
{
  const int l = threadIdx.x;
  const int m0 = blockIdx.x * 32;
  const int hc = blockIdx.y * 16;
  const int lr = l & 15, quad = l >> 4;

  const ushort* base;
  int rs;
  if (t == 0) { base = h0;                 rs = 1024;   }
  else        { base = hs + (t - 1) * 1024; rs = 262144; }

  f32x4 acc[2][5] = {};
  const ushort* a0p = base + (m0 + lr) * rs + quad * 8;
  const ushort* a1p = a0p + 16 * rs;
  const ushort* wp = Whb + (hc + lr) * 1024 + quad * 8;

#pragma unroll 2
  for (int k0 = 0; k0 < 1024; k0 += 32) {
    bf16x8 a0 = *(const bf16x8*)(a0p + k0);
    bf16x8 a1 = *(const bf16x8*)(a1p + k0);
    bf16x8 b0 = *(const bf16x8*)(wp + k0);
    bf16x8 b1 = *(const bf16x8*)(wp + 1048576 + k0);
    bf16x8 b2 = *(const bf16x8*)(wp + 2097152 + k0);
    bf16x8 b3 = *(const bf16x8*)(wp + 3145728 + k0);
    bf16x8 b4 = *(const bf16x8*)(wp + 4194304 + k0);
    acc[0][0] = MFMA16(a0, b0, acc[0][0]);
    acc[1][0] = MFMA16(a1, b0, acc[1][0]);
    acc[0][1] = MFMA16(a0, b1, acc[0][1]);
    acc[1][1] = MFMA16(a1, b1, acc[1][1]);
    acc[0][2] = MFMA16(a0, b2, acc[0][2]);
    acc[1][2] = MFMA16(a1, b2, acc[1][2]);
    acc[0][3] = MFMA16(a0, b3, acc[0][3]);
    acc[1][3] = MFMA16(a1, b3, acc[1][3]);
    acc[0][4] = MFMA16(a0, b4, acc[0][4]);
    acc[1][4] = MFMA16(a1, b4, acc[1][4]);
  }

  const int h = hc + lr;
#pragma unroll
  for (int i = 0; i < 2; ++i) {
#pragma unroll
    for (int r = 0; r < 4; ++r) {
      int b = m0 + i * 16 + quad * 4 + r;
      int prow = ((b << lc) + tloc) * 5120;
      float pi = b2f(P[prow + h])          + acc[i][0][r];
      float pf = b2f(P[prow + 1024 + h])   + acc[i][1][r];
      float pg = b2f(P[prow + 2048 + h])   + acc[i][2][r];
      float po = b2f(P[prow + 3072 + h])   + acc[i][3][r];
      float pd = b2f(P[prow + 4096 + h])   + acc[i][4][r];
      float ig = sigm(pi), fg = sigm(pf), gg = tanhfast(pg);
      float og = sigm(po), dg = sigm(pd);
      float cold = cbuf[b * 1024 + h];
      float cnew = fg * cold + ig * gg + dg;
      cbuf[b * 1024 + h] = cnew;
      hs[(b * 256 + t) * 1024 + h] = f2b(og * tanhfast(cnew));
    }
  }
}

// ---------------------------------------------------------------------------
// Kernel 3: y = tanh(x@Wro^T + hs@Who^T + Wrb), f32 out. Grid (256, 8).
// ---------------------------------------------------------------------------
__global__ __launch_bounds__(256) void gemm_post(
    const ushort* __restrict__ xb, const ushort* __restrict__ hs,
    const ushort* __restrict__ Wrob, const ushort* __restrict__ Whob,
    const float* __restrict__ Wrb, float* __restrict__ y)
{
  __shared__ __align__(16) ushort As[4096], Bs[4096];
  const int m0 = blockIdx.x * 128;
  const int n0 = blockIdx.y * 128;
  f32x4 acc[4][4] = {};
  gemm_kloop(xb + m0 * 512,  512,  Wrob + n0 * 512,  512,  512,  As, Bs, acc);
  gemm_kloop(hs + m0 * 1024, 1024, Whob + n0 * 1024, 1024, 1024, As, Bs, acc);

  const int tid = threadIdx.x;
  const int l = tid & 63, w = tid >> 6;
  const int wm = (w >> 1) * 64, wn = (w & 1) * 64;
  const int lr = l & 15, quad = l >> 4;
#pragma unroll
  for (int i = 0; i < 4; ++i)
#pragma unroll
    for (int j = 0; j < 4; ++j) {
      int row = m0 + wm + i * 16 + quad * 4;
      int col = n0 + wn + j * 16 + lr;
      float bias = Wrb[col];
#pragma unroll
      for (int r = 0; r < 4; ++r)
        y[(row + r) * 1024 + col] = tanhfast(acc[i][j][r] + bias);
    }
}

// ---------------------------------------------------------------------------
// finish: h_last (= hs[:,255,:], bf16->f32) and c_last (f32) into d_out tail.
// ---------------------------------------------------------------------------
__global__ __launch_bounds__(256) void finish_kernel(
    const ushort* __restrict__ hs, const float* __restrict__ cbuf,
    float* __restrict__ out_tail)
{
  int i = blockIdx.x * 256 + threadIdx.x;
  if (i < 131072) {
    int b = i >> 10, h = i & 1023;
    out_tail[i] = b2f(hs[(b * 256 + 255) * 1024 + h]);
    out_tail[131072 + i] = cbuf[i];
  }
}

// ---------------------------------------------------------------------------
extern "C" void kernel_launch(void* const* d_in, const int* in_sizes, int n_in,
                              void* d_out, int out_size, void* d_ws, size_t ws_size,
                              hipStream_t stream)
{
  const float* x   = (const float*)d_in[0];
  const float* xd  = (const float*)d_in[1];
  const float* hid = (const float*)d_in[2];
  const float* cel = (const float*)d_in[3];
  const float* Win[6] = {(const float*)d_in[4], (const float*)d_in[5],
                         (const float*)d_in[6], (const float*)d_in[7],
                         (const float*)d_in[8], (const float*)d_in[9]};
  const float* Whn[5] = {(const float*)d_in[10], (const float*)d_in[11],
                         (const float*)d_in[12], (const float*)d_in[13],
                         (const float*)d_in[14]};
  const float* bia[5] = {(const float*)d_in[15], (const float*)d_in[16],
                         (const float*)d_in[17], (const float*)d_in[18],
                         (const float*)d_in[19]};
  const float* Wrb = (const float*)d_in[20];
  float* y = (float*)d_out;

  // ws carve (bytes):
  char* ws = (char*)d_ws;
  ushort* xb    = (ushort*)(ws);                  //  33,554,432
  ushort* xdb   = (ushort*)(ws + 33554432);       //  33,554,432
  ushort* Wb    = (ushort*)(ws + 67108864);       //   6,291,456 (6x 1024x512)
  ushort* Whb   = (ushort*)(ws + 73400320);       //  10,485,760 (5x 1024x1024)
  ushort* hs    = (ushort*)(ws + 83886080);       //  67,108,864
  ushort* h0    = (ushort*)(ws + 150994944);      //     262,144
  float*  cbuf  = (float*) (ws + 151519232);      //     524,288
  float*  bias5 = (float*) (ws + 152043520);      //      20,480
  unsigned int* flags = (unsigned int*)(ws + 152064000);  // 4,096 (barrier)
  ushort* P     = (ushort*)(ws + 152068096);      // chunk*1,310,720

  // Largest pow2 chunk (divisor of 256) whose P fits; floor at 1.
  int chunk = 1;
  for (int c = 256; c >= 1; c >>= 1)
    if (152068096ull + (unsigned long long)c * 1310720ull <= (unsigned long long)ws_size) {
      chunk = c; break;
    }
  int lc = 31 - __builtin_clz((unsigned)chunk);

  // --- conversions f32 -> bf16 ---
  cvt_kernel<<<16384, 256, 0, stream>>>(x,  xb,  16777216);
  cvt_kernel<<<16384, 256, 0, stream>>>(xd, xdb, 16777216);
  for (int i = 0; i < 6; ++i)
    cvt_kernel<<<512, 256, 0, stream>>>(Win[i], Wb + i * 524288, 524288);
  for (int i = 0; i < 5; ++i)
    cvt_kernel<<<1024, 256, 0, stream>>>(Whn[i], Whb + i * 1048576, 1048576);
  cvt_kernel<<<128, 256, 0, stream>>>(hid, h0, 131072);
  hipMemcpyAsync(cbuf, cel, 131072 * 4, hipMemcpyDeviceToDevice, stream);
  for (int i = 0; i < 5; ++i)
    hipMemcpyAsync(bias5 + i * 1024, bia[i], 4096, hipMemcpyDeviceToDevice, stream);
  hipMemsetAsync(flags, 0, 4096, stream);   // reset barrier generations per run

  // --- pipeline ---
  int t = 0;
  bool coop_ok = true;
  for (int c = 0; c < 256 / chunk; ++c) {
    gemm_pre<<<dim3(chunk, 40), 256, 0, stream>>>(xb, xdb, Wb, bias5, P,
                                                  c * chunk, lc);
    if (coop_ok) {
      int t0 = c * chunk;
      void* args[] = {&h0, &cbuf, &Whb, &P, &hs, &flags, &t0, &chunk, &lc};
      hipError_t e = hipLaunchCooperativeKernel((const void*)lstm_chunk,
                                                dim3(256), dim3(256),
                                                args, 0, stream);
      if (e == hipSuccess) {
        t += chunk;
        continue;
      }
      coop_ok = false;  // fall through to per-step path
    }
    for (int tt = 0; tt < chunk; ++tt, ++t)
      lstm_step<<<dim3(4, 64), 64, 0, stream>>>(h0, cbuf, Whb, P, hs,
                                                t, tt, lc);
  }
  gemm_post<<<dim3(256, 8), 256, 0, stream>>>(xb, hs, Wb + 5 * 524288,
                                              Whb + 3 * 1048576, Wrb, y);
  finish_kernel<<<512, 256, 0, stream>>>(hs, cbuf, y + 33554432);
}

// Round 4
// 3988.404 us; speedup vs baseline: 3.0496x; 1.2046x over previous
//
#include <hip/hip_runtime.h>

// Problem: new_LSTM_30365418783418  (B=128, T=256, I=512, H=1024)
// R8: tree barrier + prefetch-under-wait.
//  - R7 proved fences were the big cost (41.5 -> 15.6 us/step) but pipes are
//    still >90% idle. Remaining theory: 65536 threads atomic-polling 16 cache
//    lines (arrival flags) throttles both detection and flag-store visibility.
//  - This round: two-phase barrier. Arrivals: flags[bid]=gen (1 store/block).
//    Block0/wave0 alone polls the 256 flags (64 lanes x uint4), posts a single
//    'release' word. Everyone else polls ONLY release -- all 64 lanes of a
//    wave read the SAME address => coalesced to 1 request/wave (1024 total).
//    No exit __syncthreads: each wave proceeds when it sees release.
//  - P prefetch for step t+1 issued between flag-post and poll (HBM latency
//    hides under barrier wait). Elementwise now uses all 256 threads.
//
// d_in: 0:x 1:x_d 2:hidden 3:cell | 4..9: Wii,Wif,Wig,Wio,Wid,Wro (H,I)
//       10..14: Whi,Whf,Whg,Who,Whd (H,H) | 15..20: bi,bf,bg,bo,bd,Wrb (H,)
// d_out: y(128,256,1024) ++ h_last(128,1024) ++ c_last(128,1024), float32.

using bf16x8 = __attribute__((ext_vector_type(8))) __bf16;
using f32x4  = __attribute__((ext_vector_type(4))) float;

#define MFMA16(a, b, c) __builtin_amdgcn_mfma_f32_16x16x32_bf16(a, b, c, 0, 0, 0)

static __device__ __forceinline__ float b2f(ushort u) {
  union { unsigned int i; float f; } v; v.i = ((unsigned int)u) << 16; return v.f;
}
static __device__ __forceinline__ ushort f2b(float f) {
  union { float f; unsigned int i; } v; v.f = f;
  unsigned int x = v.i;
  return (ushort)((x + 0x7fffu + ((x >> 16) & 1u)) >> 16);  // RNE
}
static __device__ __forceinline__ float sigm(float x) {
  return 1.0f / (1.0f + __expf(-x));
}
static __device__ __forceinline__ float tanhfast(float x) {
  float e = __expf(2.0f * x);          // tanh = 1 - 2/(e^{2x}+1); saturates
  return 1.0f - 2.0f / (e + 1.0f);
}

// ---------------------------------------------------------------------------
// f32 -> bf16 conversion, 4 elems/thread. n % 4 == 0.
// ---------------------------------------------------------------------------
__global__ __launch_bounds__(256) void cvt_kernel(const float* __restrict__ src,
                                                  ushort* __restrict__ dst, int n)
{
  int i = (blockIdx.x * 256 + threadIdx.x) * 4;
  if (i < n) {
    float4 v = *(const float4*)(src + i);
    ushort4 o;
    o.x = f2b(v.x); o.y = f2b(v.y); o.z = f2b(v.z); o.w = f2b(v.w);
    *(ushort4*)(dst + i) = o;
  }
}

// ---------------------------------------------------------------------------
// Generic 128x128 NT bf16 GEMM K-loop, plain-load LDS staging.
// ---------------------------------------------------------------------------
static __device__ __forceinline__ void gemm_kloop(
    const ushort* __restrict__ A, int lda,
    const ushort* __restrict__ Bw, int ldb, int K,
    ushort* As, ushort* Bs, f32x4 (&acc)[4][4])
{
  const int tid = threadIdx.x;
  const int l = tid & 63, w = tid >> 6;
  const int wm = (w >> 1) * 64, wn = (w & 1) * 64;
  const int lr = l & 15, quad = l >> 4;
  bf16x8* Asv = (bf16x8*)As;
  bf16x8* Bsv = (bf16x8*)Bs;
  for (int k0 = 0; k0 < K; k0 += 32) {
    __syncthreads();
#pragma unroll
    for (int it = 0; it < 2; ++it) {
      int c = it * 256 + tid;
      int row = c >> 2, seg = c & 3;
      Asv[c] = *(const bf16x8*)(A  + row * lda + k0 + seg * 8);
      Bsv[c] = *(const bf16x8*)(Bw + row * ldb + k0 + seg * 8);
    }
    __syncthreads();
    bf16x8 af[4], bfr[4];
#pragma unroll
    for (int i = 0; i < 4; ++i) af[i]  = Asv[(wm + i * 16 + lr) * 4 + quad];
#pragma unroll
    for (int j = 0; j < 4; ++j) bfr[j] = Bsv[(wn + j * 16 + lr) * 4 + quad];
#pragma unroll
    for (int i = 0; i < 4; ++i)
#pragma unroll
      for (int j = 0; j < 4; ++j)
        acc[i][j] = MFMA16(af[i], bfr[j], acc[i][j]);
  }
}

// ---------------------------------------------------------------------------
// Kernel 1 (per chunk): P[m'][g*1024+h] = bf16( A[b, t0+tt] . Wg[h] + bias )
// m' = b*chunk + tt. Grid (chunk, 40), 256 threads.
// ---------------------------------------------------------------------------
__global__ __launch_bounds__(256) void gemm_pre(
    const ushort* __restrict__ xb, const ushort* __restrict__ xdb,
    const ushort* __restrict__ Wb,      // 6x(1024x512) contiguous (Wii..Wid,Wro)
    const float* __restrict__ bias5, ushort* __restrict__ P,
    int t0, int lc)
{
  __shared__ __align__(16) ushort As[4096], Bs[4096];
  const int m0 = blockIdx.x * 128;
  const int n0 = blockIdx.y * 128;
  const int g = n0 >> 10;
  const ushort* A = (g == 4) ? xdb : xb;
  const ushort* Bw = Wb + g * 524288 + (n0 & 1023) * 512;
  const int cm1 = (1 << lc) - 1;

  const int tid = threadIdx.x;
  const int l = tid & 63, w = tid >> 6;
  const int wm = (w >> 1) * 64, wn = (w & 1) * 64;
  const int lr = l & 15, quad = l >> 4;
  f32x4 acc[4][4] = {};
  bf16x8* Asv = (bf16x8*)As;
  bf16x8* Bsv = (bf16x8*)Bs;

  for (int k0 = 0; k0 < 512; k0 += 32) {
    __syncthreads();
#pragma unroll
    for (int it = 0; it < 2; ++it) {
      int c = it * 256 + tid;
      int row = c >> 2, seg = c & 3;
      int gr = m0 + row;                              // m' row
      int arow = ((gr >> lc) << 8) + t0 + (gr & cm1); // b*T + t
      Asv[c] = *(const bf16x8*)(A  + arow * 512 + k0 + seg * 8);
      Bsv[c] = *(const bf16x8*)(Bw + row  * 512 + k0 + seg * 8);
    }
    __syncthreads();
    bf16x8 af[4], bfr[4];
#pragma unroll
    for (int i = 0; i < 4; ++i) af[i]  = Asv[(wm + i * 16 + lr) * 4 + quad];
#pragma unroll
    for (int j = 0; j < 4; ++j) bfr[j] = Bsv[(wn + j * 16 + lr) * 4 + quad];
#pragma unroll
    for (int i = 0; i < 4; ++i)
#pragma unroll
      for (int j = 0; j < 4; ++j)
        acc[i][j] = MFMA16(af[i], bfr[j], acc[i][j]);
  }

#pragma unroll
  for (int i = 0; i < 4; ++i)
#pragma unroll
    for (int j = 0; j < 4; ++j) {
      int row = m0 + wm + i * 16 + quad * 4;   // C/D: row = quad*4+reg (m89)
      int col = n0 + wn + j * 16 + lr;         //      col = lane&15
      float bias = bias5[col];
#pragma unroll
      for (int r = 0; r < 4; ++r)
        P[(row + r) * 5120 + col] = f2b(acc[i][j][r] + bias);
    }
}

// ---------------------------------------------------------------------------
// R8 persistent recurrent kernel (cooperative). Grid 256 x 256 threads.
// Block nb owns h-cols nb*4..+3, all 5 gates. Weights in LDS (loaded once).
// h_{t-1} read from hs (per-step-unique addresses, plain cached loads);
// h_t written via agent-scope relaxed atomic b32 (write-through, vmcnt-drained
// by __syncthreads before the arrival flag is posted).
// ---------------------------------------------------------------------------
__global__ __launch_bounds__(256, 1) void lstm_chunk(
    const ushort* __restrict__ h0,
    float* __restrict__ cbuf, const ushort* __restrict__ Whb,
    const ushort* __restrict__ P, ushort* __restrict__ hs,
    unsigned int* __restrict__ flags, unsigned int* __restrict__ release,
    int t0, int nt, int lc)
{
  __shared__ __align__(16) ushort Bs0[32 * 64 * 8];   // 32KB gates i,f,g,o
  __shared__ __align__(16) ushort Bs1[32 * 64 * 8];   // 32KB gate d (+zeros)
  __shared__ float Pls[128 * 21];                     // preacts, pad 21
  __shared__ float cs[128 * 5];                       // cell slice, pad 5

  const int tid = threadIdx.x;
  const int l = tid & 63, w = tid >> 6;
  const int lr = l & 15, quad = l >> 4;
  const int nb = blockIdx.x;                          // 0..255

  // ---- Bs0 fragments: local n = lr (gate lr>>2, hc lr&3), once ----
  {
    const ushort* wp = Whb + (((lr >> 2) << 10) + nb * 4 + (lr & 3)) * 1024 + quad * 8;
#pragma unroll
    for (int kk = 0; kk < 8; ++kk) {
      int k = w * 8 + kk;
      *(bf16x8*)(Bs0 + (k * 64 + l) * 8) = *(const bf16x8*)(wp + k * 32);
    }
  }
  // ---- Bs1 fragments: gate 4 on lanes lr<4, zero elsewhere ----
  {
    const ushort* wp = Whb + (4096 + nb * 4 + (lr & 3)) * 1024 + quad * 8;
#pragma unroll
    for (int kk = 0; kk < 8; ++kk) {
      int k = w * 8 + kk;
      bf16x8 v = {};
      if (lr < 4) v = *(const bf16x8*)(wp + k * 32);
      *(bf16x8*)(Bs1 + (k * 64 + l) * 8) = v;
    }
  }
  // ---- cell slice -> LDS ----
  if (tid < 128) {
    float4 cv = *(const float4*)(cbuf + tid * 1024 + nb * 4);
    cs[tid * 5 + 0] = cv.x; cs[tid * 5 + 1] = cv.y;
    cs[tid * 5 + 2] = cv.z; cs[tid * 5 + 3] = cv.w;
  }
  __syncthreads();

  const bf16x8* B0v = (const bf16x8*)Bs0;
  const bf16x8* B1v = (const bf16x8*)Bs1;

  // elementwise mapping: thread -> (batch row eb, col pair hp)
  const int eb = tid >> 1;
  const int hp = (tid & 1) * 2;

  // prefetch P for step 0
  ushort2 q0, q1, q2, q3, q4;
  {
    const int prow = ((eb << lc) + 0) * 5120 + nb * 4 + hp;
    q0 = *(const ushort2*)(P + prow);
    q1 = *(const ushort2*)(P + prow + 1024);
    q2 = *(const ushort2*)(P + prow + 2048);
    q3 = *(const ushort2*)(P + prow + 3072);
    q4 = *(const ushort2*)(P + prow + 4096);
  }

  for (int tt = 0; tt < nt; ++tt) {
    const int t = t0 + tt;
    // h_{t-1} source: initial h0 (stride 1024) or hs row t-1 (stride 256*1024)
    const ushort* base;
    int rs;
    if (t == 0) { base = h0;                 rs = 1024;   }
    else        { base = hs + (t - 1) * 1024; rs = 262144; }
    const ushort* a0p = base + (w * 32 + lr) * rs + quad * 8;
    const ushort* a1p = a0p + 16 * rs;

    f32x4 acc[2][2] = {};
#pragma unroll
    for (int k = 0; k < 32; ++k) {
      bf16x8 a0 = *(const bf16x8*)(a0p + k * 32);
      bf16x8 a1 = *(const bf16x8*)(a1p + k * 32);
      bf16x8 b0 = B0v[k * 64 + l];
      bf16x8 b1 = B1v[k * 64 + l];
      acc[0][0] = MFMA16(a0, b0, acc[0][0]);
      acc[1][0] = MFMA16(a1, b0, acc[1][0]);
      acc[0][1] = MFMA16(a0, b1, acc[0][1]);
      acc[1][1] = MFMA16(a1, b1, acc[1][1]);
    }

    // C/D mapping (m89): row = quad*4+reg, col = lane&15
#pragma unroll
    for (int i = 0; i < 2; ++i) {
      int b = w * 32 + i * 16 + quad * 4;
#pragma unroll
      for (int r = 0; r < 4; ++r)
        Pls[(b + r) * 21 + lr] = acc[i][0][r];
      if (lr < 4) {
#pragma unroll
        for (int r = 0; r < 4; ++r)
          Pls[(b + r) * 21 + 16 + lr] = acc[i][1][r];
      }
    }
    __syncthreads();

    // ---- elementwise: all 256 threads, 2 h-cols each ----
    {
      const float* pr = Pls + eb * 21;
      float pi0 = b2f(q0.x) + pr[0 + hp],  pi1 = b2f(q0.y) + pr[1 + hp];
      float pf0 = b2f(q1.x) + pr[4 + hp],  pf1 = b2f(q1.y) + pr[5 + hp];
      float pg0 = b2f(q2.x) + pr[8 + hp],  pg1 = b2f(q2.y) + pr[9 + hp];
      float po0 = b2f(q3.x) + pr[12 + hp], po1 = b2f(q3.y) + pr[13 + hp];
      float pd0 = b2f(q4.x) + pr[16 + hp], pd1 = b2f(q4.y) + pr[17 + hp];
      float c0 = cs[eb * 5 + hp], c1 = cs[eb * 5 + hp + 1];
      float cn0 = sigm(pf0) * c0 + sigm(pi0) * tanhfast(pg0) + sigm(pd0);
      float cn1 = sigm(pf1) * c1 + sigm(pi1) * tanhfast(pg1) + sigm(pd1);
      cs[eb * 5 + hp] = cn0;
      cs[eb * 5 + hp + 1] = cn1;
      union { ushort2 s; unsigned int u; } hu;
      hu.s.x = f2b(sigm(po0) * tanhfast(cn0));
      hu.s.y = f2b(sigm(po1) * tanhfast(cn1));
      __hip_atomic_store(
          (unsigned int*)(hs + (eb * 256 + t) * 1024 + nb * 4 + hp),
          hu.u, __ATOMIC_RELAXED, __HIP_MEMORY_SCOPE_AGENT);
    }

    if (tt + 1 < nt) {
      const unsigned int g = (unsigned int)(t + 1);
      __syncthreads();   // every thread's h-store drained (vmcnt0) before this
      if (tid == 0) {
        asm volatile("s_waitcnt vmcnt(0)" ::: "memory");
        __hip_atomic_store(flags + nb, g, __ATOMIC_RELAXED,
                           __HIP_MEMORY_SCOPE_AGENT);
      }
      // prefetch next step's P while waiting (independent of h)
      {
        const int prow = ((eb << lc) + tt + 1) * 5120 + nb * 4 + hp;
        q0 = *(const ushort2*)(P + prow);
        q1 = *(const ushort2*)(P + prow + 1024);
        q2 = *(const ushort2*)(P + prow + 2048);
        q3 = *(const ushort2*)(P + prow + 3072);
        q4 = *(const ushort2*)(P + prow + 4096);
      }
      // block0/wave0: gather arrivals, post release
      if (nb == 0 && tid < 64) {
        for (;;) {
          unsigned int f0 = __hip_atomic_load(flags + tid * 4 + 0,
                              __ATOMIC_RELAXED, __HIP_MEMORY_SCOPE_AGENT);
          unsigned int f1 = __hip_atomic_load(flags + tid * 4 + 1,
                              __ATOMIC_RELAXED, __HIP_MEMORY_SCOPE_AGENT);
          unsigned int f2 = __hip_atomic_load(flags + tid * 4 + 2,
                              __ATOMIC_RELAXED, __HIP_MEMORY_SCOPE_AGENT);
          unsigned int f3 = __hip_atomic_load(flags + tid * 4 + 3,
                              __ATOMIC_RELAXED, __HIP_MEMORY_SCOPE_AGENT);
          bool ok = (f0 >= g) & (f1 >= g) & (f2 >= g) & (f3 >= g);
          if (__all(ok)) break;
          __builtin_amdgcn_s_sleep(1);
        }
        if (tid == 0)
          __hip_atomic_store(release, g, __ATOMIC_RELAXED,
                             __HIP_MEMORY_SCOPE_AGENT);
      }
      // everyone: poll the single release word (same addr per wave -> 1 req)
      while (__hip_atomic_load(release, __ATOMIC_RELAXED,
                               __HIP_MEMORY_SCOPE_AGENT) < g) {
        __builtin_amdgcn_s_sleep(1);
      }
      asm volatile("" ::: "memory");   // no load hoisting above the poll
      // no exit __syncthreads needed: next Pls write happens after this
      // wave's K-loop; cs access gated by the post-Pls __syncthreads.
    }
  }

  // ---- cell slice back to global (each thread wrote its own cs entries) ----
  *(float2*)(cbuf + eb * 1024 + nb * 4 + hp) = *(float2*)(cs + eb * 5 + hp);
}

// ---------------------------------------------------------------------------
// Fallback kernel (x256): one LSTM step. Grid (4,64) x 64 threads.
// ---------------------------------------------------------------------------
__global__ __launch_bounds__(64) void lstm_step(
    const ushort* __restrict__ h0, float* __restrict__ cbuf,
    const ushort* __restrict__ Whb, const ushort* __restrict__ P,
    ushort* __restrict__ hs, int t, int tloc, int lc)
{
  const int l = threadIdx.x;
  const int m0 = blockIdx.x * 32;
  const int hc = blockIdx.y * 16;
  const int lr = l & 15, quad = l >> 4;

  const ushort* base;
  int rs;
  if (t == 0) { base = h0;                 rs = 1024;   }
  else        { base = hs + (t - 1) * 1024; rs = 262144; }

  f32x4 acc[2][5] = {};
  const ushort* a0p = base + (m0 + lr) * rs + quad * 8;
  const ushort* a1p = a0p + 16 * rs;
  const ushort* wp = Whb + (hc + lr) * 1024 + quad * 8;

#pragma unroll 2
  for (int k0 = 0; k0 < 1024; k0 += 32) {
    bf16x8 a0 = *(const bf16x8*)(a0p + k0);
    bf16x8 a1 = *(const bf16x8*)(a1p + k0);
    bf16x8 b0 = *(const bf16x8*)(wp + k0);
    bf16x8 b1 = *(const bf16x8*)(wp + 1048576 + k0);
    bf16x8 b2 = *(const bf16x8*)(wp + 2097152 + k0);
    bf16x8 b3 = *(const bf16x8*)(wp + 3145728 + k0);
    bf16x8 b4 = *(const bf16x8*)(wp + 4194304 + k0);
    acc[0][0] = MFMA16(a0, b0, acc[0][0]);
    acc[1][0] = MFMA16(a1, b0, acc[1][0]);
    acc[0][1] = MFMA16(a0, b1, acc[0][1]);
    acc[1][1] = MFMA16(a1, b1, acc[1][1]);
    acc[0][2] = MFMA16(a0, b2, acc[0][2]);
    acc[1][2] = MFMA16(a1, b2, acc[1][2]);
    acc[0][3] = MFMA16(a0, b3, acc[0][3]);
    acc[1][3] = MFMA16(a1, b3, acc[1][3]);
    acc[0][4] = MFMA16(a0, b4, acc[0][4]);
    acc[1][4] = MFMA16(a1, b4, acc[1][4]);
  }

  const int h = hc + lr;
#pragma unroll
  for (int i = 0; i < 2; ++i) {
#pragma unroll
    for (int r = 0; r < 4; ++r) {
      int b = m0 + i * 16 + quad * 4 + r;
      int prow = ((b << lc) + tloc) * 5120;
      float pi = b2f(P[prow + h])          + acc[i][0][r];
      float pf = b2f(P[prow + 1024 + h])   + acc[i][1][r];
      float pg = b2f(P[prow + 2048 + h])   + acc[i][2][r];
      float po = b2f(P[prow + 3072 + h])   + acc[i][3][r];
      float pd = b2f(P[prow + 4096 + h])   + acc[i][4][r];
      float ig = sigm(pi), fg = sigm(pf), gg = tanhfast(pg);
      float og = sigm(po), dg = sigm(pd);
      float cold = cbuf[b * 1024 + h];
      float cnew = fg * cold + ig * gg + dg;
      cbuf[b * 1024 + h] = cnew;
      hs[(b * 256 + t) * 1024 + h] = f2b(og * tanhfast(cnew));
    }
  }
}

// ---------------------------------------------------------------------------
// Kernel 3: y = tanh(x@Wro^T + hs@Who^T + Wrb), f32 out. Grid (256, 8).
// ---------------------------------------------------------------------------
__global__ __launch_bounds__(256) void gemm_post(
    const ushort* __restrict__ xb, const ushort* __restrict__ hs,
    const ushort* __restrict__ Wrob, const ushort* __restrict__ Whob,
    const float* __restrict__ Wrb, float* __restrict__ y)
{
  __shared__ __align__(16) ushort As[4096], Bs[4096];
  const int m0 = blockIdx.x * 128;
  const int n0 = blockIdx.y * 128;
  f32x4 acc[4][4] = {};
  gemm_kloop(xb + m0 * 512,  512,  Wrob + n0 * 512,  512,  512,  As, Bs, acc);
  gemm_kloop(hs + m0 * 1024, 1024, Whob + n0 * 1024, 1024, 1024, As, Bs, acc);

  const int tid = threadIdx.x;
  const int l = tid & 63, w = tid >> 6;
  const int wm = (w >> 1) * 64, wn = (w & 1) * 64;
  const int lr = l & 15, quad = l >> 4;
#pragma unroll
  for (int i = 0; i < 4; ++i)
#pragma unroll
    for (int j = 0; j < 4; ++j) {
      int row = m0 + wm + i * 16 + quad * 4;
      int col = n0 + wn + j * 16 + lr;
      float bias = Wrb[col];
#pragma unroll
      for (int r = 0; r < 4; ++r)
        y[(row + r) * 1024 + col] = tanhfast(acc[i][j][r] + bias);
    }
}

// ---------------------------------------------------------------------------
// finish: h_last (= hs[:,255,:], bf16->f32) and c_last (f32) into d_out tail.
// ---------------------------------------------------------------------------
__global__ __launch_bounds__(256) void finish_kernel(
    const ushort* __restrict__ hs, const float* __restrict__ cbuf,
    float* __restrict__ out_tail)
{
  int i = blockIdx.x * 256 + threadIdx.x;
  if (i < 131072) {
    int b = i >> 10, h = i & 1023;
    out_tail[i] = b2f(hs[(b * 256 + 255) * 1024 + h]);
    out_tail[131072 + i] = cbuf[i];
  }
}

// ---------------------------------------------------------------------------
extern "C" void kernel_launch(void* const* d_in, const int* in_sizes, int n_in,
                              void* d_out, int out_size, void* d_ws, size_t ws_size,
                              hipStream_t stream)
{
  const float* x   = (const float*)d_in[0];
  const float* xd  = (const float*)d_in[1];
  const float* hid = (const float*)d_in[2];
  const float* cel = (const float*)d_in[3];
  const float* Win[6] = {(const float*)d_in[4], (const float*)d_in[5],
                         (const float*)d_in[6], (const float*)d_in[7],
                         (const float*)d_in[8], (const float*)d_in[9]};
  const float* Whn[5] = {(const float*)d_in[10], (const float*)d_in[11],
                         (const float*)d_in[12], (const float*)d_in[13],
                         (const float*)d_in[14]};
  const float* bia[5] = {(const float*)d_in[15], (const float*)d_in[16],
                         (const float*)d_in[17], (const float*)d_in[18],
                         (const float*)d_in[19]};
  const float* Wrb = (const float*)d_in[20];
  float* y = (float*)d_out;

  // ws carve (bytes):
  char* ws = (char*)d_ws;
  ushort* xb    = (ushort*)(ws);                  //  33,554,432
  ushort* xdb   = (ushort*)(ws + 33554432);       //  33,554,432
  ushort* Wb    = (ushort*)(ws + 67108864);       //   6,291,456 (6x 1024x512)
  ushort* Whb   = (ushort*)(ws + 73400320);       //  10,485,760 (5x 1024x1024)
  ushort* hs    = (ushort*)(ws + 83886080);       //  67,108,864
  ushort* h0    = (ushort*)(ws + 150994944);      //     262,144
  float*  cbuf  = (float*) (ws + 151519232);      //     524,288
  float*  bias5 = (float*) (ws + 152043520);      //      20,480
  unsigned int* flags = (unsigned int*)(ws + 152064000);  // 4,096 (barrier)
  unsigned int* release = flags + 512;            // separate cache line
  ushort* P     = (ushort*)(ws + 152068096);      // chunk*1,310,720

  // Largest pow2 chunk (divisor of 256) whose P fits; floor at 1.
  int chunk = 1;
  for (int c = 256; c >= 1; c >>= 1)
    if (152068096ull + (unsigned long long)c * 1310720ull <= (unsigned long long)ws_size) {
      chunk = c; break;
    }
  int lc = 31 - __builtin_clz((unsigned)chunk);

  // --- conversions f32 -> bf16 ---
  cvt_kernel<<<16384, 256, 0, stream>>>(x,  xb,  16777216);
  cvt_kernel<<<16384, 256, 0, stream>>>(xd, xdb, 16777216);
  for (int i = 0; i < 6; ++i)
    cvt_kernel<<<512, 256, 0, stream>>>(Win[i], Wb + i * 524288, 524288);
  for (int i = 0; i < 5; ++i)
    cvt_kernel<<<1024, 256, 0, stream>>>(Whn[i], Whb + i * 1048576, 1048576);
  cvt_kernel<<<128, 256, 0, stream>>>(hid, h0, 131072);
  hipMemcpyAsync(cbuf, cel, 131072 * 4, hipMemcpyDeviceToDevice, stream);
  for (int i = 0; i < 5; ++i)
    hipMemcpyAsync(bias5 + i * 1024, bia[i], 4096, hipMemcpyDeviceToDevice, stream);
  hipMemsetAsync(flags, 0, 4096, stream);   // reset barrier generations per run

  // --- pipeline ---
  int t = 0;
  bool coop_ok = true;
  for (int c = 0; c < 256 / chunk; ++c) {
    gemm_pre<<<dim3(chunk, 40), 256, 0, stream>>>(xb, xdb, Wb, bias5, P,
                                                  c * chunk, lc);
    if (coop_ok) {
      int t0 = c * chunk;
      void* args[] = {&h0, &cbuf, &Whb, &P, &hs, &flags, &release,
                      &t0, &chunk, &lc};
      hipError_t e = hipLaunchCooperativeKernel((const void*)lstm_chunk,
                                                dim3(256), dim3(256),
                                                args, 0, stream);
      if (e == hipSuccess) {
        t += chunk;
        continue;
      }
      coop_ok = false;  // fall through to per-step path
    }
    for (int tt = 0; tt < chunk; ++tt, ++t)
      lstm_step<<<dim3(4, 64), 64, 0, stream>>>(h0, cbuf, Whb, P, hs,
                                                t, tt, lc);
  }
  gemm_post<<<dim3(256, 8), 256, 0, stream>>>(xb, hs, Wb + 5 * 524288,
                                              Whb + 3 * 1048576, Wrb, y);
  finish_kernel<<<512, 256, 0, stream>>>(hs, cbuf, y + 33554432);
}